// Round 8
// baseline (191.428 us; speedup 1.0000x reference)
//
#include <hip/hip_runtime.h>
#include <hip/hip_bf16.h>
#include <stdint.h>

typedef __bf16 bf16;
typedef __bf16 bf16x4 __attribute__((ext_vector_type(4)));
typedef __bf16 bf16x8 __attribute__((ext_vector_type(8)));
typedef float  f32x4  __attribute__((ext_vector_type(4)));
typedef float  f32x16 __attribute__((ext_vector_type(16)));

#define MFMA16(a,b,c) __builtin_amdgcn_mfma_f32_16x16x32_bf16((a),(b),(c),0,0,0)
#define MFMA32(a,b,c) __builtin_amdgcn_mfma_f32_32x32x16_bf16((a),(b),(c),0,0,0)

#define TSEQ 2048
#define NE   1024
#define NE3  3072
#define NH   16
#define HD   64
#define MTOK 4096   // BATCH*TSEQ

#if defined(__has_builtin) && __has_builtin(__builtin_amdgcn_exp2f)
#define EXP2F(x) __builtin_amdgcn_exp2f(x)
#else
__device__ __forceinline__ float exp2_fast(float x) {
  float r; asm("v_exp_f32 %0, %1" : "=v"(r) : "v"(x)); return r;
}
#define EXP2F(x) exp2_fast(x)
#endif

__device__ __forceinline__ unsigned cvt_pk_bf16(float lo, float hi) {
  unsigned r;
  asm("v_cvt_pk_bf16_f32 %0, %1, %2" : "=v"(r) : "v"(lo), "v"(hi));
  return r;
}
// v_permlane32_swap_b32 a, b: a[32:63] <-> b[0:31].
// After: a = {a_lo, b_lo-half data}, b = {a_hi-half data, b_hi}.
__device__ __forceinline__ void permlane32_swap(unsigned& a, unsigned& b) {
  asm("v_permlane32_swap_b32 %0, %1" : "+v"(a), "+v"(b));
}

// async global->LDS, 16B per lane; LDS dest = wave-uniform base + lane*16
__device__ __forceinline__ void gl_lds16(const bf16* g, bf16* l) {
  __builtin_amdgcn_global_load_lds(
      (const __attribute__((address_space(1))) void*)g,
      (__attribute__((address_space(3))) void*)l,
      16, 0, 0);
}

// ---------------- cast f32 -> bf16 (vectorized) ----------------
__global__ void k_cast(const float* __restrict__ in, bf16* __restrict__ out, int n4) {
  int i = blockIdx.x * blockDim.x + threadIdx.x;
  if (i < n4) {
    float4 v = reinterpret_cast<const float4*>(in)[i];
    bf16x4 o = { (bf16)v.x, (bf16)v.y, (bf16)v.z, (bf16)v.w };
    reinterpret_cast<bf16x4*>(out)[i] = o;
  }
}

// ---------------- weight prep: z<3 transpose wq/wk/wv; z==3 transpose wp2; z==4 cast wp1 ----
__global__ void k_transpose_all(const float* __restrict__ wq, const float* __restrict__ wk,
                                const float* __restrict__ wv, const float* __restrict__ wp2,
                                const float* __restrict__ wp1,
                                bf16* __restrict__ W3T, bf16* __restrict__ Wp2T,
                                bf16* __restrict__ Wp1b) {
  __shared__ float tile[64][65];
  const int z = blockIdx.z;
  const int r0 = blockIdx.y * 64, c0 = blockIdx.x * 64;
  const int lc = threadIdx.x & 63, lr0 = threadIdx.x >> 6;
  if (z == 4) {
#pragma unroll
    for (int i = 0; i < 16; ++i) {
      int lr = i*4 + lr0;
      Wp1b[(size_t)(r0 + lr)*1024 + c0 + lc] = (bf16)wp1[(size_t)(r0 + lr)*1024 + c0 + lc];
    }
    return;
  }
  const float* in = (z == 0) ? wq : (z == 1) ? wk : (z == 2) ? wv : wp2;
  bf16* out = (z < 3) ? (W3T + (size_t)z * 1024 * 1024) : Wp2T;
#pragma unroll
  for (int i = 0; i < 16; ++i) {
    int lr = i*4 + lr0;
    tile[lr][lc] = in[(size_t)(r0 + lr) * 1024 + (c0 + lc)];
  }
  __syncthreads();
#pragma unroll
  for (int i = 0; i < 16; ++i) {
    int lr = i*4 + lr0;
    out[(size_t)(c0 + lr) * 1024 + (r0 + lc)] = (bf16)tile[lc][lr];
  }
}

// ---------------- V section of QKV [tok][3072] -> Vt [b][h][d][t] ----------------
__global__ void k_transpose_v(const bf16* __restrict__ V, bf16* __restrict__ Vt) {
  __shared__ bf16 tile[64][65];
  const int b = blockIdx.z, h = blockIdx.y, t0 = blockIdx.x * 64;
  const int lc = threadIdx.x & 63, lr0 = threadIdx.x >> 6;
#pragma unroll
  for (int i = 0; i < 16; ++i) {
    int lr = i*4 + lr0;
    tile[lr][lc] = V[(size_t)(b*TSEQ + t0 + lr)*NE3 + h*HD + lc];
  }
  __syncthreads();
#pragma unroll
  for (int i = 0; i < 16; ++i) {
    int lr = i*4 + lr0;
    Vt[((size_t)(b*NH + h)*HD + lr)*TSEQ + t0 + lc] = tile[lc][lr];
  }
}

// ---------------- GEMM: C[M,N] = A[M,K] * Bt[N,K]^T, XCD-swizzled grid ----------------
template<int BN, typename OutT>
__global__ __launch_bounds__(256) void k_gemm_bt(const bf16* __restrict__ A,
                                                 const bf16* __restrict__ Bt,
                                                 OutT* __restrict__ C,
                                                 const int M, const int N, const int K) {
  constexpr int NC = BN / 32;
  __shared__ bf16 As[2][128*32];
  __shared__ bf16 Bs[2][BN*32];
  const int tid  = threadIdx.x;
  const int lane = tid & 63;
  const int wave = tid >> 6;
  const int wr = (wave >> 1) * 64;
  const int wc = (wave & 1) * (BN/2);
  const int l15 = lane & 15;
  const int l4  = lane >> 4;

  const int nwg = gridDim.x * gridDim.y;
  int id = blockIdx.y * gridDim.x + blockIdx.x;
  id = (id & 7) * (nwg >> 3) + (id >> 3);
  const int bm = (id / gridDim.x) * 128;
  const int bn = (id % gridDim.x) * BN;

  const int srow = tid >> 2;
  const int scol = ((tid & 3) ^ ((tid >> 3) & 3)) * 8;
  const bf16* ag = A  + (size_t)(bm + srow) * K + scol;
  const bf16* bg = Bt + (size_t)(bn + srow) * K + scol;
  const int kx = (l4 ^ ((l15 >> 1) & 3)) * 8;

  f32x4 acc[4][NC] = {};

  auto stage = [&](int buf, int k0) {
    bf16* al = As[buf] + tid * 8;
    bf16* bl = Bs[buf] + tid * 8;
    gl_lds16(ag + k0,                   al);
    gl_lds16(ag + k0 + (size_t)64 * K,  al + 64*32);
    gl_lds16(bg + k0,                   bl);
    if (BN == 128) gl_lds16(bg + k0 + (size_t)64 * K, bl + 64*32);
  };

  stage(0, 0);
  __syncthreads();
  int cur = 0;
  for (int k0 = 0; k0 < K; k0 += 32) {
    if (k0 + 32 < K) stage(cur ^ 1, k0 + 32);
    bf16x8 af[4], bfr[NC];
#pragma unroll
    for (int m = 0; m < 4; ++m)
      af[m] = *reinterpret_cast<const bf16x8*>(&As[cur][(wr + m*16 + l15)*32 + kx]);
#pragma unroll
    for (int n = 0; n < NC; ++n)
      bfr[n] = *reinterpret_cast<const bf16x8*>(&Bs[cur][(wc + n*16 + l15)*32 + kx]);
#pragma unroll
    for (int m = 0; m < 4; ++m)
#pragma unroll
      for (int n = 0; n < NC; ++n)
        acc[m][n] = MFMA16(af[m], bfr[n], acc[m][n]);
    __syncthreads();
    cur ^= 1;
  }

#pragma unroll
  for (int m = 0; m < 4; ++m) {
    const int row = bm + wr + m*16 + l4*4;
#pragma unroll
    for (int n = 0; n < NC; ++n) {
      const int col = bn + wc + n*16 + l15;
#pragma unroll
      for (int r = 0; r < 4; ++r)
        C[(size_t)(row + r) * N + col] = (OutT)acc[m][n][r];
    }
  }
}

// ---------------- causal flash attention — 32x32 MFMA, in-register P ----------------
// 256 blocks x 256 threads (4 waves). Block (p, bh), p=0..7, q-chunks {p, 15-p} of
// 128 rows; wave owns 32 q-rows (col=q=lane&31). KVBLK=128, 17 iterations.
// K LDS [128 kv][64 c] (g^=row&7), V LDS [64 d][128 t] (g^=d&15), 3-buffer
// counted-vmcnt(8). Swapped QK^T (32x32, S^T), P converted to PV B-frags fully
// in-register via v_cvt_pk_bf16_f32 + v_permlane32_swap_b32 (no P LDS traffic).
__global__ __launch_bounds__(256) void k_attn(const bf16* __restrict__ QKV,
                                              const bf16* __restrict__ Vt,
                                              bf16* __restrict__ O) {
  __shared__ bf16 KVs[3][16384];      // per buf: K 16KB @0, V 16KB @8192

  const int tid  = threadIdx.x;
  const int lane = tid & 63;
  const int wave = tid >> 6;          // 0..3
  const int l31 = lane & 31;
  const int l32 = lane >> 5;

  const int x  = blockIdx.x;          // 0..255
  const int p  = x >> 5;              // pair 0..7
  const int bh = x & 31;
  const int b  = bh >> 4, h = bh & 15;

  const bf16* Qb = QKV + (size_t)b*TSEQ*NE3 +        h*HD;
  const bf16* Kb = QKV + (size_t)b*TSEQ*NE3 + 1024 + h*HD;
  const bf16* Vb = Vt  + (size_t)bh*HD*TSEQ;

  const float SC = 0.125f * 1.44269504f;

  // staging maps (256 threads, 4 K rounds + 4 V rounds, 16B each)
  const int krow0 = tid >> 3;                       // K dest row within round (0..31)
  const int kgd   = tid & 7;                        // K dest granule
  const int vrow0 = tid >> 4;                       // V dest row within round (0..15)
  const int vgd   = tid & 15;                       // V dest granule

  auto tileOf = [&](int j) { return (j <= p) ? j : (j - p - 1); };

  auto stage = [&](int buf, int t) {
    bf16* kb = &KVs[buf][0];
    bf16* vb = &KVs[buf][8192];
#pragma unroll
    for (int rr = 0; rr < 4; ++rr) {
      const int r = rr*32 + krow0;                  // K row 0..127
      const int gs = kgd ^ (r & 7);                 // pre-swizzled source granule
      gl_lds16(&Kb[(size_t)(t*128 + r)*NE3 + gs*8], kb + rr*2048 + tid*8);
    }
#pragma unroll
    for (int rr = 0; rr < 4; ++rr) {
      const int d = rr*16 + vrow0;                  // V row (d) 0..63
      const int gs = vgd ^ (d & 15);
      gl_lds16(&Vb[(size_t)d*TSEQ + t*128 + gs*8], vb + rr*2048 + tid*8);
    }
  };

  // prologue: two stages in flight (8 loads each)
  stage(0, tileOf(0));
  stage(1, tileOf(1));
  int i = 0;                                        // global iteration 0..16

  for (int ci = 0; ci < 2; ++ci) {
    const int c  = ci ? (15 - p) : p;               // active q-chunk (128 rows)
    const int qw = c*128 + wave*32;                 // this wave's first q row

    // Q as 32x32 B-frags (col=q=l31, k=16ks+8*l32+j), pre-scaled
    bf16x8 qf[4];
#pragma unroll
    for (int ks = 0; ks < 4; ++ks) {
      bf16x8 qv = *reinterpret_cast<const bf16x8*>(
          &Qb[(size_t)(qw + l31)*NE3 + ks*16 + l32*8]);
#pragma unroll
      for (int j = 0; j < 8; ++j) qv[j] = (bf16)((float)qv[j] * SC);
      qf[ks] = qv;
    }

    f32x16 ot[2] = {};                 // O^T: d = dblk*32+(r&3)+8(r>>2)+4*l32, q = l31
    float m_run = -1e30f;
    float l_part = 0.f;

    for (int t = 0; t <= c; ++t, ++i) {
      asm volatile("s_waitcnt vmcnt(8)" ::: "memory");
      __builtin_amdgcn_sched_barrier(0);
      __builtin_amdgcn_s_barrier();
      __builtin_amdgcn_sched_barrier(0);
      const int j2 = (i + 2 <= 16) ? (i + 2) : 16;
      stage((i + 2) % 3, tileOf(j2));
      __builtin_amdgcn_sched_barrier(0);

      const bf16* kbuf = &KVs[i % 3][0];
      const bf16* vbuf = &KVs[i % 3][8192];

      const int nkb = (t == c) ? (wave + 1) : 4;    // active 32-kv blocks

      // S^T[kv][q] = K Q^T  (32x32x16, 4 ksteps)
      f32x16 st[4];
#pragma unroll
      for (int kb = 0; kb < 4; ++kb) {
        if (kb >= nkb) continue;
        f32x16 acc = {};
        const int rk = kb*32 + l31;
#pragma unroll
        for (int ks = 0; ks < 4; ++ks) {
          const int g = (2*ks + l32) ^ (rk & 7);
          bf16x8 kf = *reinterpret_cast<const bf16x8*>(&kbuf[rk*64 + g*8]);
          acc = MFMA32(kf, qf[ks], acc);
        }
        st[kb] = acc;
      }

      // diagonal mask (only block kb==wave is partial)
      if (t == c) {
#pragma unroll
        for (int r = 0; r < 16; ++r) {
          const int o = (r & 3) + 8*(r >> 2) + 4*l32;
          if (o > l31) st[wave][r] = -1e30f;
        }
      }

      // row max (q = l31 shared by lane pair (lane, lane^32))
      float mx = -1e30f;
#pragma unroll
      for (int kb = 0; kb < 4; ++kb) {
        if (kb >= nkb) continue;
#pragma unroll
        for (int r = 0; r < 16; ++r) mx = fmaxf(mx, st[kb][r]);
      }
      mx = fmaxf(mx, __shfl_xor(mx, 32));

      if (__any(mx > m_run + 8.f)) {   // T13 defer-max
        const float mnew = fmaxf(m_run, mx);
        const float corr = EXP2F(m_run - mnew);
        l_part *= corr;
#pragma unroll
        for (int dbl = 0; dbl < 2; ++dbl) ot[dbl] *= corr;
        m_run = mnew;
      }

      // P = exp2(st - m); convert to PV B-frags in-register (8 cvt_pk + 4 swaps / block)
      bf16x8 pb[8];
#pragma unroll
      for (int kb = 0; kb < 4; ++kb) {
        if (kb >= nkb) continue;
        float pv[16];
#pragma unroll
        for (int r = 0; r < 16; ++r) {
          pv[r] = EXP2F(st[kb][r] - m_run);
          l_part += pv[r];
        }
        unsigned c01 = cvt_pk_bf16(pv[0],  pv[1]);
        unsigned c23 = cvt_pk_bf16(pv[2],  pv[3]);
        unsigned c45 = cvt_pk_bf16(pv[4],  pv[5]);
        unsigned c67 = cvt_pk_bf16(pv[6],  pv[7]);
        unsigned c89 = cvt_pk_bf16(pv[8],  pv[9]);
        unsigned cAB = cvt_pk_bf16(pv[10], pv[11]);
        unsigned cCD = cvt_pk_bf16(pv[12], pv[13]);
        unsigned cEF = cvt_pk_bf16(pv[14], pv[15]);
        permlane32_swap(c01, c45);     // -> w0, w2 of frag 2kb
        permlane32_swap(c23, c67);     // -> w1, w3
        permlane32_swap(c89, cCD);     // -> w0, w2 of frag 2kb+1
        permlane32_swap(cAB, cEF);     // -> w1, w3
        union { unsigned u[4]; bf16x8 v; } f0, f1;
        f0.u[0] = c01; f0.u[1] = c23; f0.u[2] = c45; f0.u[3] = c67;
        f1.u[0] = c89; f1.u[1] = cAB; f1.u[2] = cCD; f1.u[3] = cEF;
        pb[2*kb]     = f0.v;
        pb[2*kb + 1] = f1.v;
      }

      // O^T += V^T P^T   (A = V^T frag: row=d, k=kv)
#pragma unroll
      for (int dbl = 0; dbl < 2; ++dbl) {
        const int d = dbl*32 + l31;
        f32x16 acc = ot[dbl];
#pragma unroll
        for (int ksv = 0; ksv < 8; ++ksv) {
          if (ksv >= 2*nkb) continue;
          const int g = (2*ksv + l32) ^ (d & 15);
          bf16x8 vf = *reinterpret_cast<const bf16x8*>(&vbuf[d*128 + g*8]);
          acc = MFMA32(vf, pb[ksv], acc);
        }
        ot[dbl] = acc;
      }
    }

    // chunk epilogue: l-reduce over lane pair, normalize, store
    float l = l_part + __shfl_xor(l_part, 32);
    const float rl = 1.f / l;
    const size_t row = (size_t)(b*TSEQ + qw + l31);
#pragma unroll
    for (int dbl = 0; dbl < 2; ++dbl)
#pragma unroll
      for (int u = 0; u < 4; ++u) {
        const int d0 = dbl*32 + u*8 + 4*l32;
        bf16x4 ov;
#pragma unroll
        for (int v = 0; v < 4; ++v) ov[v] = (bf16)(ot[dbl][u*4 + v] * rl);
        *reinterpret_cast<bf16x4*>(&O[row*NE + h*HD + d0]) = ov;
      }
  }
}

// ---------------- launch ----------------
extern "C" void kernel_launch(void* const* d_in, const int* in_sizes, int n_in,
                              void* d_out, int out_size, void* d_ws, size_t ws_size,
                              hipStream_t stream) {
  const float* x   = (const float*)d_in[0];
  const float* wq  = (const float*)d_in[1];
  const float* wk  = (const float*)d_in[2];
  const float* wv  = (const float*)d_in[3];
  const float* wp1 = (const float*)d_in[4];
  const float* wp2 = (const float*)d_in[5];
  float* out = (float*)d_out;

  char* ws = (char*)d_ws;
  const size_t MB = 1024ull * 1024ull;
  bf16* xb   = (bf16*)(ws + 0*MB);    // 8 MB  [4096][1024]
  bf16* W3T  = (bf16*)(ws + 8*MB);    // 6 MB  [3072][1024]
  bf16* wp1b = (bf16*)(ws + 14*MB);   // 2 MB  [1024 hd][1024 c]
  bf16* wp2T = (bf16*)(ws + 16*MB);   // 2 MB  [1024 e][1024 c]
  bf16* WcT  = (bf16*)(ws + 18*MB);   // 2 MB  [1024 e][1024 hd]
  bf16* QKVb = (bf16*)(ws + 20*MB);   // 24 MB [4096][3072]
  bf16* Vtb  = (bf16*)(ws + 44*MB);   // 8 MB  [b][h][d][t]
  bf16* attb = (bf16*)(ws + 52*MB);   // 8 MB  (total 60 MB)

  k_cast<<<4096, 256, 0, stream>>>(x, xb, MTOK*NE/4);
  k_transpose_all<<<dim3(16, 16, 5), 256, 0, stream>>>(wq, wk, wv, wp2, wp1,
                                                       W3T, wp2T, wp1b);

  // fused projection weight: WcT[e][hd] = sum_c wp2T[e][c] * wp1b[hd][c]
  k_gemm_bt<64, bf16><<<dim3(16, 8), 256, 0, stream>>>(wp2T, wp1b, WcT, 1024, 1024, 1024);

  // fused QKV projection
  k_gemm_bt<128, bf16><<<dim3(24, 32), 256, 0, stream>>>(xb, W3T, QKVb, MTOK, NE3, NE);

  // V transpose for PV operand
  k_transpose_v<<<dim3(TSEQ/64, NH, 2), 256, 0, stream>>>(QKVb + 2048, Vtb);

  // causal flash attention (32x32 MFMA, in-register P, counted-vmcnt pipeline)
  k_attn<<<dim3(256), 256, 0, stream>>>(QKVb, Vtb, attb);

  // single fused output projection: out = att * Wc
  k_gemm_bt<128, float><<<dim3(8, 32), 256, 0, stream>>>(attb, WcT, out, MTOK, NE, NE);
}

// Round 10
// 136.951 us; speedup vs baseline: 1.3978x; 1.3978x over previous
//
#include <hip/hip_runtime.h>
#include <hip/hip_bf16.h>
#include <stdint.h>

typedef __bf16 bf16;
typedef __bf16 bf16x4 __attribute__((ext_vector_type(4)));
typedef __bf16 bf16x8 __attribute__((ext_vector_type(8)));
typedef float  f32x4  __attribute__((ext_vector_type(4)));
typedef float  f32x16 __attribute__((ext_vector_type(16)));

#define MFMA16(a,b,c) __builtin_amdgcn_mfma_f32_16x16x32_bf16((a),(b),(c),0,0,0)
#define MFMA32(a,b,c) __builtin_amdgcn_mfma_f32_32x32x16_bf16((a),(b),(c),0,0,0)

#define TSEQ 2048
#define NE   1024
#define NE3  3072
#define NH   16
#define HD   64
#define MTOK 4096   // BATCH*TSEQ

#if defined(__has_builtin) && __has_builtin(__builtin_amdgcn_exp2f)
#define EXP2F(x) __builtin_amdgcn_exp2f(x)
#else
__device__ __forceinline__ float exp2_fast(float x) {
  float r; asm("v_exp_f32 %0, %1" : "=v"(r) : "v"(x)); return r;
}
#define EXP2F(x) exp2_fast(x)
#endif

__device__ __forceinline__ unsigned cvt_pk_bf16(float lo, float hi) {
  unsigned r;
  asm("v_cvt_pk_bf16_f32 %0, %1, %2" : "=v"(r) : "v"(lo), "v"(hi));
  return r;
}
__device__ __forceinline__ void permlane32_swap(unsigned& a, unsigned& b) {
  asm("v_permlane32_swap_b32 %0, %1" : "+v"(a), "+v"(b));
}

// async global->LDS, 16B per lane; LDS dest = wave-uniform base + lane*16
__device__ __forceinline__ void gl_lds16(const bf16* g, bf16* l) {
  __builtin_amdgcn_global_load_lds(
      (const __attribute__((address_space(1))) void*)g,
      (__attribute__((address_space(3))) void*)l,
      16, 0, 0);
}

// ---------------- cast f32 -> bf16 (vectorized) ----------------
__global__ void k_cast(const float* __restrict__ in, bf16* __restrict__ out, int n4) {
  int i = blockIdx.x * blockDim.x + threadIdx.x;
  if (i < n4) {
    float4 v = reinterpret_cast<const float4*>(in)[i];
    bf16x4 o = { (bf16)v.x, (bf16)v.y, (bf16)v.z, (bf16)v.w };
    reinterpret_cast<bf16x4*>(out)[i] = o;
  }
}

// ---------------- weight prep: z<3 transpose wq/wk/wv; z==3 transpose wp2; z==4 cast wp1 ----
__global__ void k_transpose_all(const float* __restrict__ wq, const float* __restrict__ wk,
                                const float* __restrict__ wv, const float* __restrict__ wp2,
                                const float* __restrict__ wp1,
                                bf16* __restrict__ W3T, bf16* __restrict__ Wp2T,
                                bf16* __restrict__ Wp1b) {
  __shared__ float tile[64][65];
  const int z = blockIdx.z;
  const int r0 = blockIdx.y * 64, c0 = blockIdx.x * 64;
  const int lc = threadIdx.x & 63, lr0 = threadIdx.x >> 6;
  if (z == 4) {
#pragma unroll
    for (int i = 0; i < 16; ++i) {
      int lr = i*4 + lr0;
      Wp1b[(size_t)(r0 + lr)*1024 + c0 + lc] = (bf16)wp1[(size_t)(r0 + lr)*1024 + c0 + lc];
    }
    return;
  }
  const float* in = (z == 0) ? wq : (z == 1) ? wk : (z == 2) ? wv : wp2;
  bf16* out = (z < 3) ? (W3T + (size_t)z * 1024 * 1024) : Wp2T;
#pragma unroll
  for (int i = 0; i < 16; ++i) {
    int lr = i*4 + lr0;
    tile[lr][lc] = in[(size_t)(r0 + lr) * 1024 + (c0 + lc)];
  }
  __syncthreads();
#pragma unroll
  for (int i = 0; i < 16; ++i) {
    int lr = i*4 + lr0;
    out[(size_t)(c0 + lr) * 1024 + (r0 + lc)] = (bf16)tile[lc][lr];
  }
}

// ---------------- V section of QKV [tok][3072] -> Vt [b][h][d][t] ----------------
__global__ void k_transpose_v(const bf16* __restrict__ V, bf16* __restrict__ Vt) {
  __shared__ bf16 tile[64][65];
  const int b = blockIdx.z, h = blockIdx.y, t0 = blockIdx.x * 64;
  const int lc = threadIdx.x & 63, lr0 = threadIdx.x >> 6;
#pragma unroll
  for (int i = 0; i < 16; ++i) {
    int lr = i*4 + lr0;
    tile[lr][lc] = V[(size_t)(b*TSEQ + t0 + lr)*NE3 + h*HD + lc];
  }
  __syncthreads();
#pragma unroll
  for (int i = 0; i < 16; ++i) {
    int lr = i*4 + lr0;
    Vt[((size_t)(b*NH + h)*HD + lr)*TSEQ + t0 + lc] = tile[lc][lr];
  }
}

// ---------------- GEMM: C[M,N] = A[M,K] * Bt[N,K]^T, XCD-swizzled grid ----------------
template<int BN, typename OutT>
__global__ __launch_bounds__(256) void k_gemm_bt(const bf16* __restrict__ A,
                                                 const bf16* __restrict__ Bt,
                                                 OutT* __restrict__ C,
                                                 const int M, const int N, const int K) {
  constexpr int NC = BN / 32;
  __shared__ bf16 As[2][128*32];
  __shared__ bf16 Bs[2][BN*32];
  const int tid  = threadIdx.x;
  const int lane = tid & 63;
  const int wave = tid >> 6;
  const int wr = (wave >> 1) * 64;
  const int wc = (wave & 1) * (BN/2);
  const int l15 = lane & 15;
  const int l4  = lane >> 4;

  const int nwg = gridDim.x * gridDim.y;
  int id = blockIdx.y * gridDim.x + blockIdx.x;
  id = (id & 7) * (nwg >> 3) + (id >> 3);
  const int bm = (id / gridDim.x) * 128;
  const int bn = (id % gridDim.x) * BN;

  const int srow = tid >> 2;
  const int scol = ((tid & 3) ^ ((tid >> 3) & 3)) * 8;
  const bf16* ag = A  + (size_t)(bm + srow) * K + scol;
  const bf16* bg = Bt + (size_t)(bn + srow) * K + scol;
  const int kx = (l4 ^ ((l15 >> 1) & 3)) * 8;

  f32x4 acc[4][NC] = {};

  auto stage = [&](int buf, int k0) {
    bf16* al = As[buf] + tid * 8;
    bf16* bl = Bs[buf] + tid * 8;
    gl_lds16(ag + k0,                   al);
    gl_lds16(ag + k0 + (size_t)64 * K,  al + 64*32);
    gl_lds16(bg + k0,                   bl);
    if (BN == 128) gl_lds16(bg + k0 + (size_t)64 * K, bl + 64*32);
  };

  stage(0, 0);
  __syncthreads();
  int cur = 0;
  for (int k0 = 0; k0 < K; k0 += 32) {
    if (k0 + 32 < K) stage(cur ^ 1, k0 + 32);
    bf16x8 af[4], bfr[NC];
#pragma unroll
    for (int m = 0; m < 4; ++m)
      af[m] = *reinterpret_cast<const bf16x8*>(&As[cur][(wr + m*16 + l15)*32 + kx]);
#pragma unroll
    for (int n = 0; n < NC; ++n)
      bfr[n] = *reinterpret_cast<const bf16x8*>(&Bs[cur][(wc + n*16 + l15)*32 + kx]);
#pragma unroll
    for (int m = 0; m < 4; ++m)
#pragma unroll
      for (int n = 0; n < NC; ++n)
        acc[m][n] = MFMA16(af[m], bfr[n], acc[m][n]);
    __syncthreads();
    cur ^= 1;
  }

#pragma unroll
  for (int m = 0; m < 4; ++m) {
    const int row = bm + wr + m*16 + l4*4;
#pragma unroll
    for (int n = 0; n < NC; ++n) {
      const int col = bn + wc + n*16 + l15;
#pragma unroll
      for (int r = 0; r < 4; ++r)
        C[(size_t)(row + r) * N + col] = (OutT)acc[m][n][r];
    }
  }
}

// ---------------- causal flash attention — 32x32 MFMA, 8 waves, kv-split ----------------
// 256 blocks x 512 threads. Block (p, bh), p=0..7, q-chunks {p, 15-p} of 128 rows.
// Wave = (kvh = wave>>2, wq4 = wave&3): q-tile wq4 (32 rows), kv half kvh (64 of 128).
// 17 iterations, KVBLK=128. K LDS [2 cpanels][128][32], V LDS [4 tpanels][64][32]
// (64B rows, (row>>1)&3 granule XOR, both-sides). 2-buffer counted-vmcnt(4) pipeline.
// P kept in registers (cvt_pk + permlane32_swap). Halves merged per chunk via LDS.
// R10 fixes vs R9: l pair-sum before merge (NaN fix); __syncthreads() in merge.
__global__ __launch_bounds__(512) void k_attn(const bf16* __restrict__ QKV,
                                              const bf16* __restrict__ Vt,
                                              bf16* __restrict__ O) {
  __shared__ bf16 KVs[2][16384];      // per buf: K 16KB @0, V 16KB @8192
  __shared__ float Mrg[4][64][36];    // per high-wave: 32 ot + m + l (+2 pad), 144B/lane

  const int tid  = threadIdx.x;
  const int lane = tid & 63;
  const int wave = tid >> 6;          // 0..7
  const int wq4  = wave & 3;          // q-tile within chunk
  const int kvh  = wave >> 2;         // kv half
  const int l31 = lane & 31;
  const int l32 = lane >> 5;

  const int x  = blockIdx.x;          // 0..255
  const int p  = x >> 5;              // pair 0..7
  const int bh = x & 31;
  const int b  = bh >> 4, h = bh & 15;

  const bf16* Qb = QKV + (size_t)b*TSEQ*NE3 +        h*HD;
  const bf16* Kb = QKV + (size_t)b*TSEQ*NE3 + 1024 + h*HD;
  const bf16* Vb = Vt  + (size_t)bh*HD*TSEQ;

  const float SC = 0.125f * 1.44269504f;

  // staging maps (512 threads, 2 K + 2 V gl_lds16 each)
  const int ksr  = tid >> 2;                        // K row 0..127
  const int ksgs = (tid & 3) ^ ((ksr >> 1) & 3);    // pre-swizzled source granule
  const int vsd  = (tid & 255) >> 2;                // V d 0..63
  const int vsgs = (tid & 3) ^ ((vsd >> 1) & 3);
  const int vsp0 = tid >> 8;                        // 0/1

  auto tileOf = [&](int j) { return (j <= p) ? j : (j - p - 1); };

  auto stage = [&](int buf, int t) {
    bf16* kb = &KVs[buf][0];
    bf16* vb = &KVs[buf][8192];
#pragma unroll
    for (int pp = 0; pp < 2; ++pp)    // K c-panels
      gl_lds16(&Kb[(size_t)(t*128 + ksr)*NE3 + pp*32 + ksgs*8], kb + pp*4096 + tid*8);
#pragma unroll
    for (int rr = 0; rr < 2; ++rr) {  // V t-panels: pt = rr*2 + vsp0
      const int pt = rr*2 + vsp0;
      gl_lds16(&Vb[(size_t)vsd*TSEQ + t*128 + pt*32 + vsgs*8], vb + rr*4096 + tid*8);
    }
  };

  stage(0, 0);
  int i = 0;                                        // global iteration 0..16

  const int kb0 = kvh*2 + 0, kb1 = kvh*2 + 1;       // this wave's kv blocks
  const int key31 = (l31 >> 1) & 3;                 // read-swizzle key (rows are +l31)

  for (int ci = 0; ci < 2; ++ci) {
    const int c  = ci ? (15 - p) : p;               // active q-chunk (128 rows)
    const int qw = c*128 + wq4*32;                  // this wave's first q row

    // Q as 32x32 B-frags (col=q=l31, k=ks*16+l32*8+j), pre-scaled
    bf16x8 qf[4];
#pragma unroll
    for (int ks = 0; ks < 4; ++ks) {
      bf16x8 qv = *reinterpret_cast<const bf16x8*>(
          &Qb[(size_t)(qw + l31)*NE3 + ks*16 + l32*8]);
#pragma unroll
      for (int j = 0; j < 8; ++j) qv[j] = (bf16)((float)qv[j] * SC);
      qf[ks] = qv;
    }

    f32x16 ot[2] = {};                 // O^T: d = dbl*32+(r&3)+8(r>>2)+4*l32, q = l31
    float m_run = -1e30f;
    float l_part = 0.f;

    for (int t = 0; t <= c; ++t, ++i) {
      __builtin_amdgcn_s_barrier();            // all waves done with buf (i+1)&1
      __builtin_amdgcn_sched_barrier(0);
      const int j1 = (i + 1 <= 16) ? (i + 1) : 16;
      stage((i + 1) & 1, tileOf(j1));
      __builtin_amdgcn_sched_barrier(0);
      asm volatile("s_waitcnt vmcnt(4)" ::: "memory");   // stage(i) landed
      __builtin_amdgcn_sched_barrier(0);

      const bf16* kbuf = &KVs[i & 1][0];
      const bf16* vbuf = &KVs[i & 1][8192];

      const bool diag = (t == c);
      const bool act0 = !diag || (kb0 <= wq4);
      const bool act1 = !diag || (kb1 <= wq4);

      // S^T[kv][q] = K Q^T  (two 32-kv blocks, named accs — no runtime indexing)
      f32x16 st0 = {}, st1 = {};
      if (act0) {
        const int rk = kb0*32 + l31;
#pragma unroll
        for (int ks = 0; ks < 4; ++ks) {
          const int g = ((ks & 1)*2 + l32) ^ key31;
          bf16x8 kf = *reinterpret_cast<const bf16x8*>(&kbuf[(ks>>1)*4096 + rk*32 + g*8]);
          st0 = MFMA32(kf, qf[ks], st0);
        }
      }
      if (act1) {
        const int rk = kb1*32 + l31;
#pragma unroll
        for (int ks = 0; ks < 4; ++ks) {
          const int g = ((ks & 1)*2 + l32) ^ key31;
          bf16x8 kf = *reinterpret_cast<const bf16x8*>(&kbuf[(ks>>1)*4096 + rk*32 + g*8]);
          st1 = MFMA32(kf, qf[ks], st1);
        }
      }

      // diagonal partial mask (static access, wave-uniform compare)
      if (diag) {
        if (kb0 == wq4) {
#pragma unroll
          for (int r = 0; r < 16; ++r) {
            const int o = (r & 3) + 8*(r >> 2) + 4*l32;
            if (o > l31) st0[r] = -1e30f;
          }
        }
        if (kb1 == wq4) {
#pragma unroll
          for (int r = 0; r < 16; ++r) {
            const int o = (r & 3) + 8*(r >> 2) + 4*l32;
            if (o > l31) st1[r] = -1e30f;
          }
        }
      }

      // row max over this wave's kv half
      float mx = -1e30f;
      if (act0) {
#pragma unroll
        for (int r = 0; r < 16; ++r) mx = fmaxf(mx, st0[r]);
      }
      if (act1) {
#pragma unroll
        for (int r = 0; r < 16; ++r) mx = fmaxf(mx, st1[r]);
      }
      mx = fmaxf(mx, __shfl_xor(mx, 32));

      if (__any(mx > m_run + 8.f)) {   // T13 defer-max
        const float mnew = fmaxf(m_run, mx);
        const float corr = EXP2F(m_run - mnew);
        l_part *= corr;
        ot[0] *= corr;
        ot[1] *= corr;
        m_run = mnew;
      }

      // P = exp2(st - m) -> PV B-frags in-register (verified mapping, R8)
      bf16x8 pb00, pb01, pb10, pb11;
      if (act0) {
        float pv[16];
#pragma unroll
        for (int r = 0; r < 16; ++r) { pv[r] = EXP2F(st0[r] - m_run); l_part += pv[r]; }
        unsigned c01 = cvt_pk_bf16(pv[0],  pv[1]),  c23 = cvt_pk_bf16(pv[2],  pv[3]);
        unsigned c45 = cvt_pk_bf16(pv[4],  pv[5]),  c67 = cvt_pk_bf16(pv[6],  pv[7]);
        unsigned c89 = cvt_pk_bf16(pv[8],  pv[9]),  cAB = cvt_pk_bf16(pv[10], pv[11]);
        unsigned cCD = cvt_pk_bf16(pv[12], pv[13]), cEF = cvt_pk_bf16(pv[14], pv[15]);
        permlane32_swap(c01, c45); permlane32_swap(c23, c67);
        permlane32_swap(c89, cCD); permlane32_swap(cAB, cEF);
        union { unsigned u[4]; bf16x8 v; } f0, f1;
        f0.u[0] = c01; f0.u[1] = c23; f0.u[2] = c45; f0.u[3] = c67;
        f1.u[0] = c89; f1.u[1] = cAB; f1.u[2] = cCD; f1.u[3] = cEF;
        pb00 = f0.v; pb01 = f1.v;
      }
      if (act1) {
        float pv[16];
#pragma unroll
        for (int r = 0; r < 16; ++r) { pv[r] = EXP2F(st1[r] - m_run); l_part += pv[r]; }
        unsigned c01 = cvt_pk_bf16(pv[0],  pv[1]),  c23 = cvt_pk_bf16(pv[2],  pv[3]);
        unsigned c45 = cvt_pk_bf16(pv[4],  pv[5]),  c67 = cvt_pk_bf16(pv[6],  pv[7]);
        unsigned c89 = cvt_pk_bf16(pv[8],  pv[9]),  cAB = cvt_pk_bf16(pv[10], pv[11]);
        unsigned cCD = cvt_pk_bf16(pv[12], pv[13]), cEF = cvt_pk_bf16(pv[14], pv[15]);
        permlane32_swap(c01, c45); permlane32_swap(c23, c67);
        permlane32_swap(c89, cCD); permlane32_swap(cAB, cEF);
        union { unsigned u[4]; bf16x8 v; } f0, f1;
        f0.u[0] = c01; f0.u[1] = c23; f0.u[2] = c45; f0.u[3] = c67;
        f1.u[0] = c89; f1.u[1] = cAB; f1.u[2] = cCD; f1.u[3] = cEF;
        pb10 = f0.v; pb11 = f1.v;
      }

      // O^T += V^T P^T  (A = V: row=d, k=kv; 64B-row panel reads)
#pragma unroll
      for (int dbl = 0; dbl < 2; ++dbl) {
        const int d = dbl*32 + l31;
        const int dkey = (d >> 1) & 3;
        f32x16 acc = ot[dbl];
        if (act0) {
#pragma unroll
          for (int kp = 0; kp < 2; ++kp) {      // κ within block kb0
            const int g = (kp*2 + l32) ^ dkey;
            bf16x8 vf = *reinterpret_cast<const bf16x8*>(&vbuf[kb0*2048 + d*32 + g*8]);
            acc = MFMA32(vf, kp ? pb01 : pb00, acc);
          }
        }
        if (act1) {
#pragma unroll
          for (int kp = 0; kp < 2; ++kp) {
            const int g = (kp*2 + l32) ^ dkey;
            bf16x8 vf = *reinterpret_cast<const bf16x8*>(&vbuf[kb1*2048 + d*32 + g*8]);
            acc = MFMA32(vf, kp ? pb11 : pb10, acc);
          }
        }
        ot[dbl] = acc;
      }
    }

    // ---- merge kv halves (waves w and w+4 share q-tile) and store ----
    // NOTE: l_part covers only this lane's half of each row (kv split across the
    // lane pair) — pair-sum FIRST (R9's missing reduction caused 0*inf = NaN).
    const float l_tot = l_part + __shfl_xor(l_part, 32);
    if (wave >= 4) {
      float4* mp4 = (float4*)&Mrg[wave - 4][lane][0];
#pragma unroll
      for (int dbl = 0; dbl < 2; ++dbl)
#pragma unroll
        for (int u = 0; u < 4; ++u) {
          float4 v = { ot[dbl][u*4+0], ot[dbl][u*4+1], ot[dbl][u*4+2], ot[dbl][u*4+3] };
          mp4[dbl*4 + u] = v;
        }
      Mrg[wave - 4][lane][32] = m_run;
      Mrg[wave - 4][lane][33] = l_tot;
    }
    __syncthreads();
    if (wave < 4) {
      const float mB = Mrg[wave][lane][32];
      const float lB = Mrg[wave][lane][33];
      const float M  = fmaxf(m_run, mB);
      const float aA = EXP2F(m_run - M);
      const float aB = EXP2F(mB - M);
      const float rl = 1.f / (l_tot*aA + lB*aB);
      const size_t row = (size_t)(b*TSEQ + qw + l31);
      const float4* mp4 = (const float4*)&Mrg[wave][lane][0];
#pragma unroll
      for (int dbl = 0; dbl < 2; ++dbl)
#pragma unroll
        for (int u = 0; u < 4; ++u) {
          const float4 vB = mp4[dbl*4 + u];
          bf16x4 ov;
          ov[0] = (bf16)((ot[dbl][u*4+0]*aA + vB.x*aB) * rl);
          ov[1] = (bf16)((ot[dbl][u*4+1]*aA + vB.y*aB) * rl);
          ov[2] = (bf16)((ot[dbl][u*4+2]*aA + vB.z*aB) * rl);
          ov[3] = (bf16)((ot[dbl][u*4+3]*aA + vB.w*aB) * rl);
          const int dbase = dbl*32 + u*8 + 4*l32;
          *reinterpret_cast<bf16x4*>(&O[row*NE + h*HD + dbase]) = ov;
        }
    }
    __syncthreads();
  }
}

// ---------------- launch ----------------
extern "C" void kernel_launch(void* const* d_in, const int* in_sizes, int n_in,
                              void* d_out, int out_size, void* d_ws, size_t ws_size,
                              hipStream_t stream) {
  const float* x   = (const float*)d_in[0];
  const float* wq  = (const float*)d_in[1];
  const float* wk  = (const float*)d_in[2];
  const float* wv  = (const float*)d_in[3];
  const float* wp1 = (const float*)d_in[4];
  const float* wp2 = (const float*)d_in[5];
  float* out = (float*)d_out;

  char* ws = (char*)d_ws;
  const size_t MB = 1024ull * 1024ull;
  bf16* xb   = (bf16*)(ws + 0*MB);    // 8 MB  [4096][1024]
  bf16* W3T  = (bf16*)(ws + 8*MB);    // 6 MB  [3072][1024]
  bf16* wp1b = (bf16*)(ws + 14*MB);   // 2 MB  [1024 hd][1024 c]
  bf16* wp2T = (bf16*)(ws + 16*MB);   // 2 MB  [1024 e][1024 c]
  bf16* WcT  = (bf16*)(ws + 18*MB);   // 2 MB  [1024 e][1024 hd]
  bf16* QKVb = (bf16*)(ws + 20*MB);   // 24 MB [4096][3072]
  bf16* Vtb  = (bf16*)(ws + 44*MB);   // 8 MB  [b][h][d][t]
  bf16* attb = (bf16*)(ws + 52*MB);   // 8 MB  (total 60 MB)

  k_cast<<<4096, 256, 0, stream>>>(x, xb, MTOK*NE/4);
  k_transpose_all<<<dim3(16, 16, 5), 256, 0, stream>>>(wq, wk, wv, wp2, wp1,
                                                       W3T, wp2T, wp1b);

  // fused projection weight: WcT[e][hd] = sum_c wp2T[e][c] * wp1b[hd][c]
  k_gemm_bt<64, bf16><<<dim3(16, 8), 256, 0, stream>>>(wp2T, wp1b, WcT, 1024, 1024, 1024);

  // fused QKV projection
  k_gemm_bt<128, bf16><<<dim3(24, 32), 256, 0, stream>>>(xb, W3T, QKVb, MTOK, NE3, NE);

  // V transpose for PV operand
  k_transpose_v<<<dim3(TSEQ/64, NH, 2), 256, 0, stream>>>(QKVb + 2048, Vtb);

  // causal flash attention (32x32 MFMA, 8 waves, kv-split, counted-vmcnt pipeline)
  k_attn<<<dim3(256), 512, 0, stream>>>(QKVb, Vtb, attb);

  // single fused output projection: out = att * Wc
  k_gemm_bt<128, float><<<dim3(8, 32), 256, 0, stream>>>(attb, WcT, out, MTOK, NE, NE);
}

// Round 11
// 125.366 us; speedup vs baseline: 1.5270x; 1.0924x over previous
//
#include <hip/hip_runtime.h>
#include <hip/hip_bf16.h>
#include <stdint.h>

typedef __bf16 bf16;
typedef __bf16 bf16x4 __attribute__((ext_vector_type(4)));
typedef __bf16 bf16x8 __attribute__((ext_vector_type(8)));
typedef float  f32x4  __attribute__((ext_vector_type(4)));

#define MFMA16(a,b,c) __builtin_amdgcn_mfma_f32_16x16x32_bf16((a),(b),(c),0,0,0)

#define TSEQ 2048
#define NE   1024
#define NE3  3072
#define NH   16
#define HD   64
#define MTOK 4096   // BATCH*TSEQ

#if defined(__has_builtin) && __has_builtin(__builtin_amdgcn_exp2f)
#define EXP2F(x) __builtin_amdgcn_exp2f(x)
#else
__device__ __forceinline__ float exp2_fast(float x) {
  float r; asm("v_exp_f32 %0, %1" : "=v"(r) : "v"(x)); return r;
}
#define EXP2F(x) exp2_fast(x)
#endif

// async global->LDS, 16B per lane; LDS dest = wave-uniform base + lane*16
__device__ __forceinline__ void gl_lds16(const bf16* g, bf16* l) {
  __builtin_amdgcn_global_load_lds(
      (const __attribute__((address_space(1))) void*)g,
      (__attribute__((address_space(3))) void*)l,
      16, 0, 0);
}

// ---------------- cast f32 -> bf16 (vectorized) ----------------
__global__ void k_cast(const float* __restrict__ in, bf16* __restrict__ out, int n4) {
  int i = blockIdx.x * blockDim.x + threadIdx.x;
  if (i < n4) {
    float4 v = reinterpret_cast<const float4*>(in)[i];
    bf16x4 o = { (bf16)v.x, (bf16)v.y, (bf16)v.z, (bf16)v.w };
    reinterpret_cast<bf16x4*>(out)[i] = o;
  }
}

// ---------------- weight prep: z<3 transpose wq/wk/wv; z==3 transpose wp2; z==4 cast wp1 ----
__global__ void k_transpose_all(const float* __restrict__ wq, const float* __restrict__ wk,
                                const float* __restrict__ wv, const float* __restrict__ wp2,
                                const float* __restrict__ wp1,
                                bf16* __restrict__ W3T, bf16* __restrict__ Wp2T,
                                bf16* __restrict__ Wp1b) {
  __shared__ float tile[64][65];
  const int z = blockIdx.z;
  const int r0 = blockIdx.y * 64, c0 = blockIdx.x * 64;
  const int lc = threadIdx.x & 63, lr0 = threadIdx.x >> 6;
  if (z == 4) {   // straight cast wp1 -> Wp1b
#pragma unroll
    for (int i = 0; i < 16; ++i) {
      int lr = i*4 + lr0;
      Wp1b[(size_t)(r0 + lr)*1024 + c0 + lc] = (bf16)wp1[(size_t)(r0 + lr)*1024 + c0 + lc];
    }
    return;
  }
  const float* in = (z == 0) ? wq : (z == 1) ? wk : (z == 2) ? wv : wp2;
  bf16* out = (z < 3) ? (W3T + (size_t)z * 1024 * 1024) : Wp2T;
#pragma unroll
  for (int i = 0; i < 16; ++i) {
    int lr = i*4 + lr0;
    tile[lr][lc] = in[(size_t)(r0 + lr) * 1024 + (c0 + lc)];
  }
  __syncthreads();
#pragma unroll
  for (int i = 0; i < 16; ++i) {
    int lr = i*4 + lr0;
    out[(size_t)(c0 + lr) * 1024 + (r0 + lc)] = (bf16)tile[lc][lr];
  }
}

// ---------------- GEMM: C[M,N] = A[M,K] * Bt[N,K]^T, XCD-swizzled grid ----------------
// VTF: for the QKV GEMM, blocks with bn >= 2048 (V columns) write their C-tile
// directly TRANSPOSED to Vt[b*16+h][d][t] (bf16x4 along t) and skip the C write.
template<int BN, typename OutT, bool VTF>
__global__ __launch_bounds__(256) void k_gemm_bt(const bf16* __restrict__ A,
                                                 const bf16* __restrict__ Bt,
                                                 OutT* __restrict__ C,
                                                 bf16* __restrict__ VtOut,
                                                 const int M, const int N, const int K) {
  constexpr int NC = BN / 32;
  __shared__ bf16 As[2][128*32];
  __shared__ bf16 Bs[2][BN*32];
  const int tid  = threadIdx.x;
  const int lane = tid & 63;
  const int wave = tid >> 6;
  const int wr = (wave >> 1) * 64;
  const int wc = (wave & 1) * (BN/2);
  const int l15 = lane & 15;
  const int l4  = lane >> 4;

  const int nwg = gridDim.x * gridDim.y;
  int id = blockIdx.y * gridDim.x + blockIdx.x;
  id = (id & 7) * (nwg >> 3) + (id >> 3);
  const int bm = (id / gridDim.x) * 128;
  const int bn = (id % gridDim.x) * BN;

  const int srow = tid >> 2;
  const int scol = ((tid & 3) ^ ((tid >> 3) & 3)) * 8;
  const bf16* ag = A  + (size_t)(bm + srow) * K + scol;
  const bf16* bg = Bt + (size_t)(bn + srow) * K + scol;
  const int kx = (l4 ^ ((l15 >> 1) & 3)) * 8;

  f32x4 acc[4][NC] = {};

  auto stage = [&](int buf, int k0) {
    bf16* al = As[buf] + tid * 8;
    bf16* bl = Bs[buf] + tid * 8;
    gl_lds16(ag + k0,                   al);
    gl_lds16(ag + k0 + (size_t)64 * K,  al + 64*32);
    gl_lds16(bg + k0,                   bl);
    if (BN == 128) gl_lds16(bg + k0 + (size_t)64 * K, bl + 64*32);
  };

  stage(0, 0);
  __syncthreads();
  int cur = 0;
  for (int k0 = 0; k0 < K; k0 += 32) {
    if (k0 + 32 < K) stage(cur ^ 1, k0 + 32);
    bf16x8 af[4], bfr[NC];
#pragma unroll
    for (int m = 0; m < 4; ++m)
      af[m] = *reinterpret_cast<const bf16x8*>(&As[cur][(wr + m*16 + l15)*32 + kx]);
#pragma unroll
    for (int n = 0; n < NC; ++n)
      bfr[n] = *reinterpret_cast<const bf16x8*>(&Bs[cur][(wc + n*16 + l15)*32 + kx]);
#pragma unroll
    for (int m = 0; m < 4; ++m)
#pragma unroll
      for (int n = 0; n < NC; ++n)
        acc[m][n] = MFMA16(af[m], bfr[n], acc[m][n]);
    __syncthreads();
    cur ^= 1;
  }

  if (VTF && bn >= 2048) {
    // V block: write transposed to Vt[bh][d][t]; t = 4 consecutive rows per lane
    const int bB  = bm >> 11;                 // batch (128 | 2048)
    const int tb0 = (bm & 2047) + wr + l4*4;
#pragma unroll
    for (int m = 0; m < 4; ++m) {
      const int tb = tb0 + m*16;
#pragma unroll
      for (int n = 0; n < NC; ++n) {
        const int dg = (bn - 2048) + wc + n*16 + l15;   // global V feature 0..1023
        bf16x4 ov;
#pragma unroll
        for (int r = 0; r < 4; ++r) ov[r] = (bf16)acc[m][n][r];
        *reinterpret_cast<bf16x4*>(
            &VtOut[((size_t)(bB*16 + (dg >> 6))*64 + (dg & 63))*2048 + tb]) = ov;
      }
    }
  } else {
#pragma unroll
    for (int m = 0; m < 4; ++m) {
      const int row = bm + wr + m*16 + l4*4;
#pragma unroll
      for (int n = 0; n < NC; ++n) {
        const int col = bn + wc + n*16 + l15;
#pragma unroll
        for (int r = 0; r < 4; ++r)
          C[(size_t)(row + r) * N + col] = (OutT)acc[m][n][r];
      }
    }
  }
}

// ---------------- causal flash attention — R6 structure (best measured) + T5 setprio ----
// 256 blocks x 512 threads. Block (p, bh), p=0..7, processes q-chunks {p, 15-p} of
// 128 rows; wave owns 16 q-rows. Exactly 17 KV-tile iterations per block (KVBLK=128).
// K LDS [2 ks][128 kv][32], V LDS [4 ksv][64 d][32], granule-swizzled both sides,
// double-buffered (stage-ahead + __syncthreads). Swapped QK^T (S^T), O^T accumulation,
// T13 defer-max, per-wave Ps.
__global__ __launch_bounds__(512) void k_attn(const bf16* __restrict__ QKV,
                                              const bf16* __restrict__ Vt,
                                              bf16* __restrict__ O) {
  __shared__ bf16 Ks[2][2*128*32];    // 2 x 16KB
  __shared__ bf16 Vs[2][4*64*32];     // 2 x 16KB
  __shared__ bf16 Ps[8][4*16*32];     // 8 x 4KB

  const int tid  = threadIdx.x;
  const int lane = tid & 63;
  const int wave = tid >> 6;          // 0..7
  const int l15 = lane & 15;
  const int l4  = lane >> 4;

  const int x  = blockIdx.x;          // 0..255
  const int p  = x >> 5;              // pair 0..7
  const int bh = x & 31;
  const int b  = bh >> 4, h = bh & 15;

  const bf16* Qb = QKV + (size_t)b*TSEQ*NE3 +        h*HD;
  const bf16* Kb = QKV + (size_t)b*TSEQ*NE3 + 1024 + h*HD;
  const bf16* Vb = Vt  + (size_t)bh*HD*TSEQ;
  bf16* Pw = Ps[wave];

  const float SC = 0.125f * 1.44269504f;
  const int swz = (l4 ^ ((l15 >> 1) & 3)) * 8;      // read-side swizzled granule (elems)
  const int key = (l15 >> 1) & 3;

  // staging maps (512 threads):
  const int krow = tid >> 2;                        // 0..127
  const int kg   = (tid & 3) ^ ((krow >> 1) & 3);
  const int vd   = (tid >> 2) & 63;
  const int vg   = (tid & 3) ^ ((vd >> 1) & 3);
  const int vp0  = tid >> 8;                        // 0 or 1

  auto stage = [&](int buf, int t) {
#pragma unroll
    for (int kk = 0; kk < 2; ++kk)
      gl_lds16(&Kb[(size_t)(t*128 + krow)*NE3 + kk*32 + kg*8],
               &Ks[buf][kk*4096 + tid*8]);
#pragma unroll
    for (int kk = 0; kk < 2; ++kk) {
      const int ksv = kk*2 + vp0;
      gl_lds16(&Vb[(size_t)vd*TSEQ + t*128 + ksv*32 + vg*8],
               &Vs[buf][kk*4096 + tid*8]);
    }
  };

  stage(0, 0);
  __syncthreads();
  int cur = 0;
  int i = 0;                                        // global iteration 0..16

  for (int ci = 0; ci < 2; ++ci) {
    const int c  = ci ? (15 - p) : p;               // active q-chunk (128 rows)
    const int qw = c*128 + wave*16;                 // this wave's first q row

    // Q as B-frag (col=q=l15, k=c), pre-scaled by 0.125*log2e
    bf16x8 qf[2];
#pragma unroll
    for (int ks = 0; ks < 2; ++ks) {
      bf16x8 qv = *reinterpret_cast<const bf16x8*>(
          &Qb[(size_t)(qw + l15)*NE3 + ks*32 + l4*8]);
#pragma unroll
      for (int j = 0; j < 8; ++j) qv[j] = (bf16)((float)qv[j] * SC);
      qf[ks] = qv;
    }

    f32x4 ot[4] = {};                  // O^T: row d = n2*16+l4*4+r, col q = qw+l15
    float m_run = -1e30f;
    float l_part = 0.f;

    for (int t = 0; t <= c; ++t, ++i) {
      if (i + 1 < 17) {
        const int nxt = (i + 1 <= p) ? (i + 1) : (i - p);
        stage(cur ^ 1, nxt);
      }

      // S^T[kv][q] = K Q^T   (128 kv x 16 q per wave)
      __builtin_amdgcn_s_setprio(1);
      f32x4 st[8];
#pragma unroll
      for (int kvf = 0; kvf < 8; ++kvf) {
        st[kvf] = f32x4{0.f, 0.f, 0.f, 0.f};
        const int row = kvf*16 + l15;
#pragma unroll
        for (int ks = 0; ks < 2; ++ks) {
          bf16x8 kf = *reinterpret_cast<const bf16x8*>(&Ks[cur][ks*4096 + row*32 + swz]);
          st[kvf] = MFMA16(kf, qf[ks], st[kvf]);
        }
      }
      __builtin_amdgcn_s_setprio(0);

      if (t == c) {                    // diagonal tile: causal mask (tile-local)
#pragma unroll
        for (int kvf = 0; kvf < 8; ++kvf)
#pragma unroll
          for (int r = 0; r < 4; ++r)
            if (kvf*16 + l4*4 + r > wave*16 + l15) st[kvf][r] = -1e30f;
      }

      float mx = st[0][0];
#pragma unroll
      for (int kvf = 0; kvf < 8; ++kvf)
#pragma unroll
        for (int r = 0; r < 4; ++r) mx = fmaxf(mx, st[kvf][r]);
      mx = fmaxf(mx, __shfl_xor(mx, 16));
      mx = fmaxf(mx, __shfl_xor(mx, 32));

      if (__any(mx > m_run + 8.f)) {   // T13 defer-max
        const float mnew = fmaxf(m_run, mx);
        const float corr = EXP2F(m_run - mnew);
        l_part *= corr;
#pragma unroll
        for (int n2 = 0; n2 < 4; ++n2) ot[n2] *= corr;
        m_run = mnew;
      }

      float rs = 0.f;
#pragma unroll
      for (int kvf = 0; kvf < 8; ++kvf) {
        bf16x4 pk;
#pragma unroll
        for (int r = 0; r < 4; ++r) {
          const float pv = EXP2F(st[kvf][r] - m_run);
          rs += pv;
          pk[r] = (bf16)pv;
        }
        const int gp = (((kvf & 1)*2 + (l4 >> 1)) ^ key);
        *reinterpret_cast<bf16x4*>(
            &Pw[(kvf>>1)*512 + l15*32 + gp*8 + (l4 & 1)*4]) = pk;
      }
      l_part += rs;

      // O^T += V^T P^T
      bf16x8 pa[4];
#pragma unroll
      for (int ksv = 0; ksv < 4; ++ksv)
        pa[ksv] = *reinterpret_cast<const bf16x8*>(&Pw[ksv*512 + l15*32 + swz]);
      __builtin_amdgcn_s_setprio(1);
#pragma unroll
      for (int n2 = 0; n2 < 4; ++n2) {
        const int vrow = n2*16 + l15;
#pragma unroll
        for (int ksv = 0; ksv < 4; ++ksv) {
          bf16x8 vf = *reinterpret_cast<const bf16x8*>(&Vs[cur][ksv*2048 + vrow*32 + swz]);
          ot[n2] = MFMA16(vf, pa[ksv], ot[n2]);
        }
      }
      __builtin_amdgcn_s_setprio(0);

      __syncthreads();
      cur ^= 1;
    }

    // chunk epilogue: reduce l across l4 groups (q lane-local), normalize, store
    float l = l_part;
    l += __shfl_xor(l, 16);
    l += __shfl_xor(l, 32);
    const float rl = 1.f / l;
    const size_t row = (size_t)(b*TSEQ + qw + l15);
#pragma unroll
    for (int n2 = 0; n2 < 4; ++n2) {
      bf16x4 ov;
#pragma unroll
      for (int r = 0; r < 4; ++r) ov[r] = (bf16)(ot[n2][r] * rl);
      *reinterpret_cast<bf16x4*>(&O[row*NE + h*HD + n2*16 + l4*4]) = ov;
    }
  }
}

// ---------------- launch ----------------
extern "C" void kernel_launch(void* const* d_in, const int* in_sizes, int n_in,
                              void* d_out, int out_size, void* d_ws, size_t ws_size,
                              hipStream_t stream) {
  const float* x   = (const float*)d_in[0];
  const float* wq  = (const float*)d_in[1];
  const float* wk  = (const float*)d_in[2];
  const float* wv  = (const float*)d_in[3];
  const float* wp1 = (const float*)d_in[4];
  const float* wp2 = (const float*)d_in[5];
  float* out = (float*)d_out;

  char* ws = (char*)d_ws;
  const size_t MB = 1024ull * 1024ull;
  bf16* xb   = (bf16*)(ws + 0*MB);    // 8 MB  [4096][1024]
  bf16* W3T  = (bf16*)(ws + 8*MB);    // 6 MB  [3072][1024]
  bf16* wp1b = (bf16*)(ws + 14*MB);   // 2 MB  [1024 hd][1024 c]
  bf16* wp2T = (bf16*)(ws + 16*MB);   // 2 MB  [1024 e][1024 c]
  bf16* WcT  = (bf16*)(ws + 18*MB);   // 2 MB  [1024 e][1024 hd]
  bf16* QKVb = (bf16*)(ws + 20*MB);   // 24 MB [4096][3072] (V region unused)
  bf16* Vtb  = (bf16*)(ws + 44*MB);   // 8 MB  [b][h][d][t]
  bf16* attb = (bf16*)(ws + 52*MB);   // 8 MB  (total 60 MB)

  k_cast<<<4096, 256, 0, stream>>>(x, xb, MTOK*NE/4);
  k_transpose_all<<<dim3(16, 16, 5), 256, 0, stream>>>(wq, wk, wv, wp2, wp1,
                                                       W3T, wp2T, wp1b);

  // fused projection weight: WcT[e][hd] = sum_c wp2T[e][c] * wp1b[hd][c]
  k_gemm_bt<64, bf16, false><<<dim3(16, 8), 256, 0, stream>>>(
      wp2T, wp1b, WcT, nullptr, 1024, 1024, 1024);

  // fused QKV projection; V columns written directly transposed to Vtb
  k_gemm_bt<128, bf16, true><<<dim3(24, 32), 256, 0, stream>>>(
      xb, W3T, QKVb, Vtb, MTOK, NE3, NE);

  // balanced causal flash attention (R6 structure + setprio)
  k_attn<<<dim3(256), 512, 0, stream>>>(QKVb, Vtb, attb);

  // single fused output projection: out = att * Wc
  k_gemm_bt<128, float, false><<<dim3(8, 32), 256, 0, stream>>>(
      attb, WcT, out, nullptr, MTOK, NE, NE);
}

// Round 12
// 123.928 us; speedup vs baseline: 1.5447x; 1.0116x over previous
//
#include <hip/hip_runtime.h>
#include <hip/hip_bf16.h>
#include <stdint.h>

typedef __bf16 bf16;
typedef __bf16 bf16x4 __attribute__((ext_vector_type(4)));
typedef __bf16 bf16x8 __attribute__((ext_vector_type(8)));
typedef float  f32x4  __attribute__((ext_vector_type(4)));

#define MFMA16(a,b,c) __builtin_amdgcn_mfma_f32_16x16x32_bf16((a),(b),(c),0,0,0)

#define TSEQ 2048
#define NE   1024
#define NE3  3072
#define NH   16
#define HD   64
#define MTOK 4096   // BATCH*TSEQ

#if defined(__has_builtin) && __has_builtin(__builtin_amdgcn_exp2f)
#define EXP2F(x) __builtin_amdgcn_exp2f(x)
#else
__device__ __forceinline__ float exp2_fast(float x) {
  float r; asm("v_exp_f32 %0, %1" : "=v"(r) : "v"(x)); return r;
}
#define EXP2F(x) exp2_fast(x)
#endif

// async global->LDS, 16B per lane; LDS dest = wave-uniform base + lane*16
__device__ __forceinline__ void gl_lds16(const bf16* g, bf16* l) {
  __builtin_amdgcn_global_load_lds(
      (const __attribute__((address_space(1))) void*)g,
      (__attribute__((address_space(3))) void*)l,
      16, 0, 0);
}

// ---------------- fused prep: x cast (blocks 0..4095) + weight prep (4096..5375) ----
// weight prep planes: z<3 transpose wq/wk/wv -> W3T; z==3 transpose wp2 -> Wp2T;
// z==4 cast wp1 -> Wp1b.
__global__ __launch_bounds__(256) void k_prep(const float* __restrict__ x,
                                              const float* __restrict__ wq,
                                              const float* __restrict__ wk,
                                              const float* __restrict__ wv,
                                              const float* __restrict__ wp2,
                                              const float* __restrict__ wp1,
                                              bf16* __restrict__ xb,
                                              bf16* __restrict__ W3T,
                                              bf16* __restrict__ Wp2T,
                                              bf16* __restrict__ Wp1b) {
  const int id = blockIdx.x;
  if (id < 4096) {              // x cast, float4 per thread
    const int i = id * 256 + threadIdx.x;
    float4 v = reinterpret_cast<const float4*>(x)[i];
    bf16x4 o = { (bf16)v.x, (bf16)v.y, (bf16)v.z, (bf16)v.w };
    reinterpret_cast<bf16x4*>(xb)[i] = o;
    return;
  }
  __shared__ float tile[64][65];
  const int wid = id - 4096;
  const int z  = wid >> 8;
  const int by = (wid >> 4) & 15, bx = wid & 15;
  const int r0 = by * 64, c0 = bx * 64;
  const int lc = threadIdx.x & 63, lr0 = threadIdx.x >> 6;
  if (z == 4) {                 // straight cast wp1 -> Wp1b
#pragma unroll
    for (int i = 0; i < 16; ++i) {
      int lr = i*4 + lr0;
      Wp1b[(size_t)(r0 + lr)*1024 + c0 + lc] = (bf16)wp1[(size_t)(r0 + lr)*1024 + c0 + lc];
    }
    return;
  }
  const float* in = (z == 0) ? wq : (z == 1) ? wk : (z == 2) ? wv : wp2;
  bf16* out = (z < 3) ? (W3T + (size_t)z * 1024 * 1024) : Wp2T;
#pragma unroll
  for (int i = 0; i < 16; ++i) {
    int lr = i*4 + lr0;
    tile[lr][lc] = in[(size_t)(r0 + lr) * 1024 + (c0 + lc)];
  }
  __syncthreads();
#pragma unroll
  for (int i = 0; i < 16; ++i) {
    int lr = i*4 + lr0;
    out[(size_t)(c0 + lr) * 1024 + (r0 + lc)] = (bf16)tile[lc][lr];
  }
}

// ---------------- merged GEMM dispatch: QKV (blocks 0..767) + WcT (768..831) ----------
// QKV: [4096,1024] x W3T[3072,1024]^T -> QKV[4096,3072]; V cols (bn>=2048) written
// transposed to Vt[b*16+h][d][t]. WcT: wp2T[1024,1024] x wp1b[1024,1024]^T -> WcT.
// Both K=1024, BM=BN=128, 4 waves, 2-phase double-buffered LDS, both-sides swizzle.
__global__ __launch_bounds__(256) void k_gemm_qkv_wc(const bf16* __restrict__ xb,
                                                     const bf16* __restrict__ W3T,
                                                     const bf16* __restrict__ wp2T,
                                                     const bf16* __restrict__ wp1b,
                                                     bf16* __restrict__ QKV,
                                                     bf16* __restrict__ Vt,
                                                     bf16* __restrict__ WcT) {
  constexpr int K = 1024;
  __shared__ bf16 As[2][128*32];
  __shared__ bf16 Bs[2][128*32];
  const int tid  = threadIdx.x;
  const int lane = tid & 63;
  const int wave = tid >> 6;
  const int wr = (wave >> 1) * 64;
  const int wc = (wave & 1) * 64;
  const int l15 = lane & 15;
  const int l4  = lane >> 4;

  const bf16 *A, *Bt; bf16 *C; int N, nbx; bool vtf;
  int id = blockIdx.x;
  if (id < 768) {
    A = xb; Bt = W3T; C = QKV; N = 3072; nbx = 24; vtf = true;
    id = (id & 7) * 96 + (id >> 3);               // XCD swizzle within segment
  } else {
    id -= 768;
    A = wp2T; Bt = wp1b; C = WcT; N = 1024; nbx = 8; vtf = false;
    id = (id & 7) * 8 + (id >> 3);
  }
  const int bm = (id / nbx) * 128;
  const int bn = (id % nbx) * 128;

  const int srow = tid >> 2;
  const int scol = ((tid & 3) ^ ((tid >> 3) & 3)) * 8;
  const bf16* ag = A  + (size_t)(bm + srow) * K + scol;
  const bf16* bg = Bt + (size_t)(bn + srow) * K + scol;
  const int kx = (l4 ^ ((l15 >> 1) & 3)) * 8;

  f32x4 acc[4][4] = {};

  auto stage = [&](int buf, int k0) {
    bf16* al = As[buf] + tid * 8;
    bf16* bl = Bs[buf] + tid * 8;
    gl_lds16(ag + k0,                  al);
    gl_lds16(ag + k0 + (size_t)64 * K, al + 64*32);
    gl_lds16(bg + k0,                  bl);
    gl_lds16(bg + k0 + (size_t)64 * K, bl + 64*32);
  };

  stage(0, 0);
  __syncthreads();
  int cur = 0;
  for (int k0 = 0; k0 < K; k0 += 32) {
    if (k0 + 32 < K) stage(cur ^ 1, k0 + 32);
    bf16x8 af[4], bfr[4];
#pragma unroll
    for (int m = 0; m < 4; ++m)
      af[m] = *reinterpret_cast<const bf16x8*>(&As[cur][(wr + m*16 + l15)*32 + kx]);
#pragma unroll
    for (int n = 0; n < 4; ++n)
      bfr[n] = *reinterpret_cast<const bf16x8*>(&Bs[cur][(wc + n*16 + l15)*32 + kx]);
#pragma unroll
    for (int m = 0; m < 4; ++m)
#pragma unroll
      for (int n = 0; n < 4; ++n)
        acc[m][n] = MFMA16(af[m], bfr[n], acc[m][n]);
    __syncthreads();
    cur ^= 1;
  }

  if (vtf && bn >= 2048) {
    // V block: write transposed to Vt[bh][d][t]; t = 4 consecutive rows per lane
    const int bB  = bm >> 11;
    const int tb0 = (bm & 2047) + wr + l4*4;
#pragma unroll
    for (int m = 0; m < 4; ++m) {
      const int tb = tb0 + m*16;
#pragma unroll
      for (int n = 0; n < 4; ++n) {
        const int dg = (bn - 2048) + wc + n*16 + l15;
        bf16x4 ov;
#pragma unroll
        for (int r = 0; r < 4; ++r) ov[r] = (bf16)acc[m][n][r];
        *reinterpret_cast<bf16x4*>(
            &Vt[((size_t)(bB*16 + (dg >> 6))*64 + (dg & 63))*2048 + tb]) = ov;
      }
    }
  } else {
#pragma unroll
    for (int m = 0; m < 4; ++m) {
      const int row = bm + wr + m*16 + l4*4;
#pragma unroll
      for (int n = 0; n < 4; ++n) {
        const int col = bn + wc + n*16 + l15;
#pragma unroll
        for (int r = 0; r < 4; ++r)
          C[(size_t)(row + r) * N + col] = (bf16)acc[m][n][r];
      }
    }
  }
}

// ---------------- out-projection GEMM: C[M,N] = A[M,K]*Bt[N,K]^T, BN=64, f32 out ----
__global__ __launch_bounds__(256) void k_gemm_out(const bf16* __restrict__ A,
                                                  const bf16* __restrict__ Bt,
                                                  float* __restrict__ C) {
  constexpr int K = 1024, N = 1024, BN = 64;
  __shared__ bf16 As[2][128*32];
  __shared__ bf16 Bs[2][BN*32];
  const int tid  = threadIdx.x;
  const int lane = tid & 63;
  const int wave = tid >> 6;
  const int wr = (wave >> 1) * 64;
  const int wc = (wave & 1) * 32;
  const int l15 = lane & 15;
  const int l4  = lane >> 4;

  const int nwg = gridDim.x * gridDim.y;
  int id = blockIdx.y * gridDim.x + blockIdx.x;
  id = (id & 7) * (nwg >> 3) + (id >> 3);
  const int bm = (id / gridDim.x) * 128;
  const int bn = (id % gridDim.x) * BN;

  const int srow = tid >> 2;
  const int scol = ((tid & 3) ^ ((tid >> 3) & 3)) * 8;
  const bf16* ag = A  + (size_t)(bm + srow) * K + scol;
  const bf16* bg = Bt + (size_t)(bn + srow) * K + scol;
  const int kx = (l4 ^ ((l15 >> 1) & 3)) * 8;

  f32x4 acc[4][2] = {};

  auto stage = [&](int buf, int k0) {
    bf16* al = As[buf] + tid * 8;
    bf16* bl = Bs[buf] + tid * 8;
    gl_lds16(ag + k0,                  al);
    gl_lds16(ag + k0 + (size_t)64 * K, al + 64*32);
    gl_lds16(bg + k0,                  bl);
  };

  stage(0, 0);
  __syncthreads();
  int cur = 0;
  for (int k0 = 0; k0 < K; k0 += 32) {
    if (k0 + 32 < K) stage(cur ^ 1, k0 + 32);
    bf16x8 af[4], bfr[2];
#pragma unroll
    for (int m = 0; m < 4; ++m)
      af[m] = *reinterpret_cast<const bf16x8*>(&As[cur][(wr + m*16 + l15)*32 + kx]);
#pragma unroll
    for (int n = 0; n < 2; ++n)
      bfr[n] = *reinterpret_cast<const bf16x8*>(&Bs[cur][(wc + n*16 + l15)*32 + kx]);
#pragma unroll
    for (int m = 0; m < 4; ++m)
#pragma unroll
      for (int n = 0; n < 2; ++n)
        acc[m][n] = MFMA16(af[m], bfr[n], acc[m][n]);
    __syncthreads();
    cur ^= 1;
  }

#pragma unroll
  for (int m = 0; m < 4; ++m) {
    const int row = bm + wr + m*16 + l4*4;
#pragma unroll
    for (int n = 0; n < 2; ++n) {
      const int col = bn + wc + n*16 + l15;
#pragma unroll
      for (int r = 0; r < 4; ++r)
        C[(size_t)(row + r) * N + col] = acc[m][n][r];
    }
  }
}

// ---------------- causal flash attention — R6 structure (best measured) ----------------
// 256 blocks x 512 threads. Block (p, bh), p=0..7, processes q-chunks {p, 15-p} of
// 128 rows; wave owns 16 q-rows. Exactly 17 KV-tile iterations per block (KVBLK=128).
// K LDS [2 ks][128 kv][32], V LDS [4 ksv][64 d][32], granule-swizzled both sides,
// double-buffered (stage-ahead + __syncthreads). Swapped QK^T (S^T), O^T accumulation,
// T13 defer-max, per-wave Ps.
__global__ __launch_bounds__(512) void k_attn(const bf16* __restrict__ QKV,
                                              const bf16* __restrict__ Vt,
                                              bf16* __restrict__ O) {
  __shared__ bf16 Ks[2][2*128*32];    // 2 x 16KB
  __shared__ bf16 Vs[2][4*64*32];     // 2 x 16KB
  __shared__ bf16 Ps[8][4*16*32];     // 8 x 4KB

  const int tid  = threadIdx.x;
  const int lane = tid & 63;
  const int wave = tid >> 6;          // 0..7
  const int l15 = lane & 15;
  const int l4  = lane >> 4;

  const int x  = blockIdx.x;          // 0..255
  const int p  = x >> 5;              // pair 0..7
  const int bh = x & 31;
  const int b  = bh >> 4, h = bh & 15;

  const bf16* Qb = QKV + (size_t)b*TSEQ*NE3 +        h*HD;
  const bf16* Kb = QKV + (size_t)b*TSEQ*NE3 + 1024 + h*HD;
  const bf16* Vb = Vt  + (size_t)bh*HD*TSEQ;
  bf16* Pw = Ps[wave];

  const float SC = 0.125f * 1.44269504f;
  const int swz = (l4 ^ ((l15 >> 1) & 3)) * 8;      // read-side swizzled granule (elems)
  const int key = (l15 >> 1) & 3;

  // staging maps (512 threads):
  const int krow = tid >> 2;                        // 0..127
  const int kg   = (tid & 3) ^ ((krow >> 1) & 3);
  const int vd   = (tid >> 2) & 63;
  const int vg   = (tid & 3) ^ ((vd >> 1) & 3);
  const int vp0  = tid >> 8;                        // 0 or 1

  auto stage = [&](int buf, int t) {
#pragma unroll
    for (int kk = 0; kk < 2; ++kk)
      gl_lds16(&Kb[(size_t)(t*128 + krow)*NE3 + kk*32 + kg*8],
               &Ks[buf][kk*4096 + tid*8]);
#pragma unroll
    for (int kk = 0; kk < 2; ++kk) {
      const int ksv = kk*2 + vp0;
      gl_lds16(&Vb[(size_t)vd*TSEQ + t*128 + ksv*32 + vg*8],
               &Vs[buf][kk*4096 + tid*8]);
    }
  };

  stage(0, 0);
  __syncthreads();
  int cur = 0;
  int i = 0;                                        // global iteration 0..16

  for (int ci = 0; ci < 2; ++ci) {
    const int c  = ci ? (15 - p) : p;               // active q-chunk (128 rows)
    const int qw = c*128 + wave*16;                 // this wave's first q row

    // Q as B-frag (col=q=l15, k=c), pre-scaled by 0.125*log2e
    bf16x8 qf[2];
#pragma unroll
    for (int ks = 0; ks < 2; ++ks) {
      bf16x8 qv = *reinterpret_cast<const bf16x8*>(
          &Qb[(size_t)(qw + l15)*NE3 + ks*32 + l4*8]);
#pragma unroll
      for (int j = 0; j < 8; ++j) qv[j] = (bf16)((float)qv[j] * SC);
      qf[ks] = qv;
    }

    f32x4 ot[4] = {};                  // O^T: row d = n2*16+l4*4+r, col q = qw+l15
    float m_run = -1e30f;
    float l_part = 0.f;

    for (int t = 0; t <= c; ++t, ++i) {
      if (i + 1 < 17) {
        const int nxt = (i + 1 <= p) ? (i + 1) : (i - p);
        stage(cur ^ 1, nxt);
      }

      // S^T[kv][q] = K Q^T   (128 kv x 16 q per wave)
      f32x4 st[8];
#pragma unroll
      for (int kvf = 0; kvf < 8; ++kvf) {
        st[kvf] = f32x4{0.f, 0.f, 0.f, 0.f};
        const int row = kvf*16 + l15;
#pragma unroll
        for (int ks = 0; ks < 2; ++ks) {
          bf16x8 kf = *reinterpret_cast<const bf16x8*>(&Ks[cur][ks*4096 + row*32 + swz]);
          st[kvf] = MFMA16(kf, qf[ks], st[kvf]);
        }
      }

      if (t == c) {                    // diagonal tile: causal mask (tile-local)
#pragma unroll
        for (int kvf = 0; kvf < 8; ++kvf)
#pragma unroll
          for (int r = 0; r < 4; ++r)
            if (kvf*16 + l4*4 + r > wave*16 + l15) st[kvf][r] = -1e30f;
      }

      float mx = st[0][0];
#pragma unroll
      for (int kvf = 0; kvf < 8; ++kvf)
#pragma unroll
        for (int r = 0; r < 4; ++r) mx = fmaxf(mx, st[kvf][r]);
      mx = fmaxf(mx, __shfl_xor(mx, 16));
      mx = fmaxf(mx, __shfl_xor(mx, 32));

      if (__any(mx > m_run + 8.f)) {   // T13 defer-max
        const float mnew = fmaxf(m_run, mx);
        const float corr = EXP2F(m_run - mnew);
        l_part *= corr;
#pragma unroll
        for (int n2 = 0; n2 < 4; ++n2) ot[n2] *= corr;
        m_run = mnew;
      }

      float rs = 0.f;
#pragma unroll
      for (int kvf = 0; kvf < 8; ++kvf) {
        bf16x4 pk;
#pragma unroll
        for (int r = 0; r < 4; ++r) {
          const float pv = EXP2F(st[kvf][r] - m_run);
          rs += pv;
          pk[r] = (bf16)pv;
        }
        const int gp = (((kvf & 1)*2 + (l4 >> 1)) ^ key);
        *reinterpret_cast<bf16x4*>(
            &Pw[(kvf>>1)*512 + l15*32 + gp*8 + (l4 & 1)*4]) = pk;
      }
      l_part += rs;

      // O^T += V^T P^T
      bf16x8 pa[4];
#pragma unroll
      for (int ksv = 0; ksv < 4; ++ksv)
        pa[ksv] = *reinterpret_cast<const bf16x8*>(&Pw[ksv*512 + l15*32 + swz]);
#pragma unroll
      for (int n2 = 0; n2 < 4; ++n2) {
        const int vrow = n2*16 + l15;
#pragma unroll
        for (int ksv = 0; ksv < 4; ++ksv) {
          bf16x8 vf = *reinterpret_cast<const bf16x8*>(&Vs[cur][ksv*2048 + vrow*32 + swz]);
          ot[n2] = MFMA16(vf, pa[ksv], ot[n2]);
        }
      }

      __syncthreads();
      cur ^= 1;
    }

    // chunk epilogue: reduce l across l4 groups (q lane-local), normalize, store
    float l = l_part;
    l += __shfl_xor(l, 16);
    l += __shfl_xor(l, 32);
    const float rl = 1.f / l;
    const size_t row = (size_t)(b*TSEQ + qw + l15);
#pragma unroll
    for (int n2 = 0; n2 < 4; ++n2) {
      bf16x4 ov;
#pragma unroll
      for (int r = 0; r < 4; ++r) ov[r] = (bf16)(ot[n2][r] * rl);
      *reinterpret_cast<bf16x4*>(&O[row*NE + h*HD + n2*16 + l4*4]) = ov;
    }
  }
}

// ---------------- launch ----------------
extern "C" void kernel_launch(void* const* d_in, const int* in_sizes, int n_in,
                              void* d_out, int out_size, void* d_ws, size_t ws_size,
                              hipStream_t stream) {
  const float* x   = (const float*)d_in[0];
  const float* wq  = (const float*)d_in[1];
  const float* wk  = (const float*)d_in[2];
  const float* wv  = (const float*)d_in[3];
  const float* wp1 = (const float*)d_in[4];
  const float* wp2 = (const float*)d_in[5];
  float* out = (float*)d_out;

  char* ws = (char*)d_ws;
  const size_t MB = 1024ull * 1024ull;
  bf16* xb   = (bf16*)(ws + 0*MB);    // 8 MB  [4096][1024]
  bf16* W3T  = (bf16*)(ws + 8*MB);    // 6 MB  [3072][1024]
  bf16* wp1b = (bf16*)(ws + 14*MB);   // 2 MB  [1024 hd][1024 c]
  bf16* wp2T = (bf16*)(ws + 16*MB);   // 2 MB  [1024 e][1024 c]
  bf16* WcT  = (bf16*)(ws + 18*MB);   // 2 MB  [1024 e][1024 hd]
  bf16* QKVb = (bf16*)(ws + 20*MB);   // 24 MB [4096][3072] (V region unused)
  bf16* Vtb  = (bf16*)(ws + 44*MB);   // 8 MB  [b][h][d][t]
  bf16* attb = (bf16*)(ws + 52*MB);   // 8 MB  (total 60 MB)

  // fused prep: x cast + all weight transposes/casts (one dispatch)
  k_prep<<<5376, 256, 0, stream>>>(x, wq, wk, wv, wp2, wp1, xb, W3T, wp2T, wp1b);

  // merged GEMM dispatch: QKV projection (+V transpose fusion) and WcT = wp2T*wp1b^T
  k_gemm_qkv_wc<<<832, 256, 0, stream>>>(xb, W3T, wp2T, wp1b, QKVb, Vtb, WcT);

  // balanced causal flash attention (R6 structure)
  k_attn<<<dim3(256), 512, 0, stream>>>(QKVb, Vtb, attb);

  // single fused output projection: out = att * Wc
  k_gemm_out<<<dim3(16, 32), 256, 0, stream>>>(attb, WcT, out);
}

// Round 13
// 122.357 us; speedup vs baseline: 1.5645x; 1.0128x over previous
//
#include <hip/hip_runtime.h>
#include <hip/hip_bf16.h>
#include <stdint.h>

typedef __bf16 bf16;
typedef __bf16 bf16x4 __attribute__((ext_vector_type(4)));
typedef __bf16 bf16x8 __attribute__((ext_vector_type(8)));
typedef float  f32x4  __attribute__((ext_vector_type(4)));

#define MFMA16(a,b,c) __builtin_amdgcn_mfma_f32_16x16x32_bf16((a),(b),(c),0,0,0)

#define TSEQ 2048
#define NE   1024
#define NE3  3072
#define NH   16
#define HD   64
#define MTOK 4096   // BATCH*TSEQ

#if defined(__has_builtin) && __has_builtin(__builtin_amdgcn_exp2f)
#define EXP2F(x) __builtin_amdgcn_exp2f(x)
#else
__device__ __forceinline__ float exp2_fast(float x) {
  float r; asm("v_exp_f32 %0, %1" : "=v"(r) : "v"(x)); return r;
}
#define EXP2F(x) exp2_fast(x)
#endif

// async global->LDS, 16B per lane; LDS dest = wave-uniform base + lane*16
__device__ __forceinline__ void gl_lds16(const bf16* g, bf16* l) {
  __builtin_amdgcn_global_load_lds(
      (const __attribute__((address_space(1))) void*)g,
      (__attribute__((address_space(3))) void*)l,
      16, 0, 0);
}

// ---------------- fused prep: x cast (blocks 0..4095) + weight prep (4096..5375) ----
__global__ __launch_bounds__(256) void k_prep(const float* __restrict__ x,
                                              const float* __restrict__ wq,
                                              const float* __restrict__ wk,
                                              const float* __restrict__ wv,
                                              const float* __restrict__ wp2,
                                              const float* __restrict__ wp1,
                                              bf16* __restrict__ xb,
                                              bf16* __restrict__ W3T,
                                              bf16* __restrict__ Wp2T,
                                              bf16* __restrict__ Wp1b) {
  const int id = blockIdx.x;
  if (id < 4096) {              // x cast, float4 per thread
    const int i = id * 256 + threadIdx.x;
    float4 v = reinterpret_cast<const float4*>(x)[i];
    bf16x4 o = { (bf16)v.x, (bf16)v.y, (bf16)v.z, (bf16)v.w };
    reinterpret_cast<bf16x4*>(xb)[i] = o;
    return;
  }
  __shared__ float tile[64][65];
  const int wid = id - 4096;
  const int z  = wid >> 8;
  const int by = (wid >> 4) & 15, bx = wid & 15;
  const int r0 = by * 64, c0 = bx * 64;
  const int lc = threadIdx.x & 63, lr0 = threadIdx.x >> 6;
  if (z == 4) {                 // straight cast wp1 -> Wp1b
#pragma unroll
    for (int i = 0; i < 16; ++i) {
      int lr = i*4 + lr0;
      Wp1b[(size_t)(r0 + lr)*1024 + c0 + lc] = (bf16)wp1[(size_t)(r0 + lr)*1024 + c0 + lc];
    }
    return;
  }
  const float* in = (z == 0) ? wq : (z == 1) ? wk : (z == 2) ? wv : wp2;
  bf16* out = (z < 3) ? (W3T + (size_t)z * 1024 * 1024) : Wp2T;
#pragma unroll
  for (int i = 0; i < 16; ++i) {
    int lr = i*4 + lr0;
    tile[lr][lc] = in[(size_t)(r0 + lr) * 1024 + (c0 + lc)];
  }
  __syncthreads();
#pragma unroll
  for (int i = 0; i < 16; ++i) {
    int lr = i*4 + lr0;
    out[(size_t)(c0 + lr) * 1024 + (r0 + lc)] = (bf16)tile[lc][lr];
  }
}

// ---------------- GEMM: C[M,N] = A[M,K] * Bt[N,K]^T, XCD-swizzled grid ----------------
// VTF: for the QKV GEMM, blocks with bn >= 2048 (V columns) write their C-tile
// directly TRANSPOSED to Vt[b*16+h][d][t] (bf16x4 along t) and skip the C write.
template<int BN, typename OutT, bool VTF>
__global__ __launch_bounds__(256) void k_gemm_bt(const bf16* __restrict__ A,
                                                 const bf16* __restrict__ Bt,
                                                 OutT* __restrict__ C,
                                                 bf16* __restrict__ VtOut,
                                                 const int M, const int N, const int K) {
  constexpr int NC = BN / 32;
  __shared__ bf16 As[2][128*32];
  __shared__ bf16 Bs[2][BN*32];
  const int tid  = threadIdx.x;
  const int lane = tid & 63;
  const int wave = tid >> 6;
  const int wr = (wave >> 1) * 64;
  const int wc = (wave & 1) * (BN/2);
  const int l15 = lane & 15;
  const int l4  = lane >> 4;

  const int nwg = gridDim.x * gridDim.y;
  int id = blockIdx.y * gridDim.x + blockIdx.x;
  id = (id & 7) * (nwg >> 3) + (id >> 3);
  const int bm = (id / gridDim.x) * 128;
  const int bn = (id % gridDim.x) * BN;

  const int srow = tid >> 2;
  const int scol = ((tid & 3) ^ ((tid >> 3) & 3)) * 8;
  const bf16* ag = A  + (size_t)(bm + srow) * K + scol;
  const bf16* bg = Bt + (size_t)(bn + srow) * K + scol;
  const int kx = (l4 ^ ((l15 >> 1) & 3)) * 8;

  f32x4 acc[4][NC] = {};

  auto stage = [&](int buf, int k0) {
    bf16* al = As[buf] + tid * 8;
    bf16* bl = Bs[buf] + tid * 8;
    gl_lds16(ag + k0,                   al);
    gl_lds16(ag + k0 + (size_t)64 * K,  al + 64*32);
    gl_lds16(bg + k0,                   bl);
    if (BN == 128) gl_lds16(bg + k0 + (size_t)64 * K, bl + 64*32);
  };

  stage(0, 0);
  __syncthreads();
  int cur = 0;
  for (int k0 = 0; k0 < K; k0 += 32) {
    if (k0 + 32 < K) stage(cur ^ 1, k0 + 32);
    bf16x8 af[4], bfr[NC];
#pragma unroll
    for (int m = 0; m < 4; ++m)
      af[m] = *reinterpret_cast<const bf16x8*>(&As[cur][(wr + m*16 + l15)*32 + kx]);
#pragma unroll
    for (int n = 0; n < NC; ++n)
      bfr[n] = *reinterpret_cast<const bf16x8*>(&Bs[cur][(wc + n*16 + l15)*32 + kx]);
#pragma unroll
    for (int m = 0; m < 4; ++m)
#pragma unroll
      for (int n = 0; n < NC; ++n)
        acc[m][n] = MFMA16(af[m], bfr[n], acc[m][n]);
    __syncthreads();
    cur ^= 1;
  }

  if (VTF && bn >= 2048) {
    // V block: write transposed to Vt[bh][d][t]; t = 4 consecutive rows per lane
    const int bB  = bm >> 11;                 // batch (128 | 2048)
    const int tb0 = (bm & 2047) + wr + l4*4;
#pragma unroll
    for (int m = 0; m < 4; ++m) {
      const int tb = tb0 + m*16;
#pragma unroll
      for (int n = 0; n < NC; ++n) {
        const int dg = (bn - 2048) + wc + n*16 + l15;   // global V feature 0..1023
        bf16x4 ov;
#pragma unroll
        for (int r = 0; r < 4; ++r) ov[r] = (bf16)acc[m][n][r];
        *reinterpret_cast<bf16x4*>(
            &VtOut[((size_t)(bB*16 + (dg >> 6))*64 + (dg & 63))*2048 + tb]) = ov;
      }
    }
  } else {
#pragma unroll
    for (int m = 0; m < 4; ++m) {
      const int row = bm + wr + m*16 + l4*4;
#pragma unroll
      for (int n = 0; n < NC; ++n) {
        const int col = bn + wc + n*16 + l15;
#pragma unroll
        for (int r = 0; r < 4; ++r)
          C[(size_t)(row + r) * N + col] = (OutT)acc[m][n][r];
      }
    }
  }
}

// ---------------- out-projection GEMM: C[M,N] = A[M,K]*Bt[N,K]^T, BN=64, f32 out ----
__global__ __launch_bounds__(256) void k_gemm_out(const bf16* __restrict__ A,
                                                  const bf16* __restrict__ Bt,
                                                  float* __restrict__ C) {
  constexpr int K = 1024, N = 1024, BN = 64;
  __shared__ bf16 As[2][128*32];
  __shared__ bf16 Bs[2][BN*32];
  const int tid  = threadIdx.x;
  const int lane = tid & 63;
  const int wave = tid >> 6;
  const int wr = (wave >> 1) * 64;
  const int wc = (wave & 1) * 32;
  const int l15 = lane & 15;
  const int l4  = lane >> 4;

  const int nwg = gridDim.x * gridDim.y;
  int id = blockIdx.y * gridDim.x + blockIdx.x;
  id = (id & 7) * (nwg >> 3) + (id >> 3);
  const int bm = (id / gridDim.x) * 128;
  const int bn = (id % gridDim.x) * BN;

  const int srow = tid >> 2;
  const int scol = ((tid & 3) ^ ((tid >> 3) & 3)) * 8;
  const bf16* ag = A  + (size_t)(bm + srow) * K + scol;
  const bf16* bg = Bt + (size_t)(bn + srow) * K + scol;
  const int kx = (l4 ^ ((l15 >> 1) & 3)) * 8;

  f32x4 acc[4][2] = {};

  auto stage = [&](int buf, int k0) {
    bf16* al = As[buf] + tid * 8;
    bf16* bl = Bs[buf] + tid * 8;
    gl_lds16(ag + k0,                  al);
    gl_lds16(ag + k0 + (size_t)64 * K, al + 64*32);
    gl_lds16(bg + k0,                  bl);
  };

  stage(0, 0);
  __syncthreads();
  int cur = 0;
  for (int k0 = 0; k0 < K; k0 += 32) {
    if (k0 + 32 < K) stage(cur ^ 1, k0 + 32);
    bf16x8 af[4], bfr[2];
#pragma unroll
    for (int m = 0; m < 4; ++m)
      af[m] = *reinterpret_cast<const bf16x8*>(&As[cur][(wr + m*16 + l15)*32 + kx]);
#pragma unroll
    for (int n = 0; n < 2; ++n)
      bfr[n] = *reinterpret_cast<const bf16x8*>(&Bs[cur][(wc + n*16 + l15)*32 + kx]);
#pragma unroll
    for (int m = 0; m < 4; ++m)
#pragma unroll
      for (int n = 0; n < 2; ++n)
        acc[m][n] = MFMA16(af[m], bfr[n], acc[m][n]);
    __syncthreads();
    cur ^= 1;
  }

#pragma unroll
  for (int m = 0; m < 4; ++m) {
    const int row = bm + wr + m*16 + l4*4;
#pragma unroll
    for (int n = 0; n < 2; ++n) {
      const int col = bn + wc + n*16 + l15;
#pragma unroll
      for (int r = 0; r < 4; ++r)
        C[(size_t)(row + r) * N + col] = acc[m][n][r];
    }
  }
}

// ---------------- causal flash attention — R6 structure (best measured) ----------------
__global__ __launch_bounds__(512) void k_attn(const bf16* __restrict__ QKV,
                                              const bf16* __restrict__ Vt,
                                              bf16* __restrict__ O) {
  __shared__ bf16 Ks[2][2*128*32];    // 2 x 16KB
  __shared__ bf16 Vs[2][4*64*32];     // 2 x 16KB
  __shared__ bf16 Ps[8][4*16*32];     // 8 x 4KB

  const int tid  = threadIdx.x;
  const int lane = tid & 63;
  const int wave = tid >> 6;          // 0..7
  const int l15 = lane & 15;
  const int l4  = lane >> 4;

  const int x  = blockIdx.x;          // 0..255
  const int p  = x >> 5;              // pair 0..7
  const int bh = x & 31;
  const int b  = bh >> 4, h = bh & 15;

  const bf16* Qb = QKV + (size_t)b*TSEQ*NE3 +        h*HD;
  const bf16* Kb = QKV + (size_t)b*TSEQ*NE3 + 1024 + h*HD;
  const bf16* Vb = Vt  + (size_t)bh*HD*TSEQ;
  bf16* Pw = Ps[wave];

  const float SC = 0.125f * 1.44269504f;
  const int swz = (l4 ^ ((l15 >> 1) & 3)) * 8;      // read-side swizzled granule (elems)
  const int key = (l15 >> 1) & 3;

  const int krow = tid >> 2;                        // 0..127
  const int kg   = (tid & 3) ^ ((krow >> 1) & 3);
  const int vd   = (tid >> 2) & 63;
  const int vg   = (tid & 3) ^ ((vd >> 1) & 3);
  const int vp0  = tid >> 8;                        // 0 or 1

  auto stage = [&](int buf, int t) {
#pragma unroll
    for (int kk = 0; kk < 2; ++kk)
      gl_lds16(&Kb[(size_t)(t*128 + krow)*NE3 + kk*32 + kg*8],
               &Ks[buf][kk*4096 + tid*8]);
#pragma unroll
    for (int kk = 0; kk < 2; ++kk) {
      const int ksv = kk*2 + vp0;
      gl_lds16(&Vb[(size_t)vd*TSEQ + t*128 + ksv*32 + vg*8],
               &Vs[buf][kk*4096 + tid*8]);
    }
  };

  stage(0, 0);
  __syncthreads();
  int cur = 0;
  int i = 0;                                        // global iteration 0..16

  for (int ci = 0; ci < 2; ++ci) {
    const int c  = ci ? (15 - p) : p;               // active q-chunk (128 rows)
    const int qw = c*128 + wave*16;                 // this wave's first q row

    bf16x8 qf[2];
#pragma unroll
    for (int ks = 0; ks < 2; ++ks) {
      bf16x8 qv = *reinterpret_cast<const bf16x8*>(
          &Qb[(size_t)(qw + l15)*NE3 + ks*32 + l4*8]);
#pragma unroll
      for (int j = 0; j < 8; ++j) qv[j] = (bf16)((float)qv[j] * SC);
      qf[ks] = qv;
    }

    f32x4 ot[4] = {};                  // O^T: row d = n2*16+l4*4+r, col q = qw+l15
    float m_run = -1e30f;
    float l_part = 0.f;

    for (int t = 0; t <= c; ++t, ++i) {
      if (i + 1 < 17) {
        const int nxt = (i + 1 <= p) ? (i + 1) : (i - p);
        stage(cur ^ 1, nxt);
      }

      f32x4 st[8];
#pragma unroll
      for (int kvf = 0; kvf < 8; ++kvf) {
        st[kvf] = f32x4{0.f, 0.f, 0.f, 0.f};
        const int row = kvf*16 + l15;
#pragma unroll
        for (int ks = 0; ks < 2; ++ks) {
          bf16x8 kf = *reinterpret_cast<const bf16x8*>(&Ks[cur][ks*4096 + row*32 + swz]);
          st[kvf] = MFMA16(kf, qf[ks], st[kvf]);
        }
      }

      if (t == c) {                    // diagonal tile: causal mask (tile-local)
#pragma unroll
        for (int kvf = 0; kvf < 8; ++kvf)
#pragma unroll
          for (int r = 0; r < 4; ++r)
            if (kvf*16 + l4*4 + r > wave*16 + l15) st[kvf][r] = -1e30f;
      }

      float mx = st[0][0];
#pragma unroll
      for (int kvf = 0; kvf < 8; ++kvf)
#pragma unroll
        for (int r = 0; r < 4; ++r) mx = fmaxf(mx, st[kvf][r]);
      mx = fmaxf(mx, __shfl_xor(mx, 16));
      mx = fmaxf(mx, __shfl_xor(mx, 32));

      if (__any(mx > m_run + 8.f)) {   // T13 defer-max
        const float mnew = fmaxf(m_run, mx);
        const float corr = EXP2F(m_run - mnew);
        l_part *= corr;
#pragma unroll
        for (int n2 = 0; n2 < 4; ++n2) ot[n2] *= corr;
        m_run = mnew;
      }

      float rs = 0.f;
#pragma unroll
      for (int kvf = 0; kvf < 8; ++kvf) {
        bf16x4 pk;
#pragma unroll
        for (int r = 0; r < 4; ++r) {
          const float pv = EXP2F(st[kvf][r] - m_run);
          rs += pv;
          pk[r] = (bf16)pv;
        }
        const int gp = (((kvf & 1)*2 + (l4 >> 1)) ^ key);
        *reinterpret_cast<bf16x4*>(
            &Pw[(kvf>>1)*512 + l15*32 + gp*8 + (l4 & 1)*4]) = pk;
      }
      l_part += rs;

      bf16x8 pa[4];
#pragma unroll
      for (int ksv = 0; ksv < 4; ++ksv)
        pa[ksv] = *reinterpret_cast<const bf16x8*>(&Pw[ksv*512 + l15*32 + swz]);
#pragma unroll
      for (int n2 = 0; n2 < 4; ++n2) {
        const int vrow = n2*16 + l15;
#pragma unroll
        for (int ksv = 0; ksv < 4; ++ksv) {
          bf16x8 vf = *reinterpret_cast<const bf16x8*>(&Vs[cur][ksv*2048 + vrow*32 + swz]);
          ot[n2] = MFMA16(vf, pa[ksv], ot[n2]);
        }
      }

      __syncthreads();
      cur ^= 1;
    }

    float l = l_part;
    l += __shfl_xor(l, 16);
    l += __shfl_xor(l, 32);
    const float rl = 1.f / l;
    const size_t row = (size_t)(b*TSEQ + qw + l15);
#pragma unroll
    for (int n2 = 0; n2 < 4; ++n2) {
      bf16x4 ov;
#pragma unroll
      for (int r = 0; r < 4; ++r) ov[r] = (bf16)(ot[n2][r] * rl);
      *reinterpret_cast<bf16x4*>(&O[row*NE + h*HD + n2*16 + l4*4]) = ov;
    }
  }
}

// ---------------- launch ----------------
extern "C" void kernel_launch(void* const* d_in, const int* in_sizes, int n_in,
                              void* d_out, int out_size, void* d_ws, size_t ws_size,
                              hipStream_t stream) {
  const float* x   = (const float*)d_in[0];
  const float* wq  = (const float*)d_in[1];
  const float* wk  = (const float*)d_in[2];
  const float* wv  = (const float*)d_in[3];
  const float* wp1 = (const float*)d_in[4];
  const float* wp2 = (const float*)d_in[5];
  float* out = (float*)d_out;

  char* ws = (char*)d_ws;
  const size_t MB = 1024ull * 1024ull;
  bf16* xb   = (bf16*)(ws + 0*MB);    // 8 MB  [4096][1024]
  bf16* W3T  = (bf16*)(ws + 8*MB);    // 6 MB  [3072][1024]
  bf16* wp1b = (bf16*)(ws + 14*MB);   // 2 MB  [1024 hd][1024 c]
  bf16* wp2T = (bf16*)(ws + 16*MB);   // 2 MB  [1024 e][1024 c]
  bf16* WcT  = (bf16*)(ws + 18*MB);   // 2 MB  [1024 e][1024 hd]
  bf16* QKVb = (bf16*)(ws + 20*MB);   // 24 MB [4096][3072] (V region unused)
  bf16* Vtb  = (bf16*)(ws + 44*MB);   // 8 MB  [b][h][d][t]
  bf16* attb = (bf16*)(ws + 52*MB);   // 8 MB  (total 60 MB)

  // fused prep: x cast + all weight transposes/casts (one dispatch)
  k_prep<<<5376, 256, 0, stream>>>(x, wq, wk, wv, wp2, wp1, xb, W3T, wp2T, wp1b);

  // fused projection weight: WcT[e][hd] = sum_c wp2T[e][c] * wp1b[hd][c]
  k_gemm_bt<64, bf16, false><<<dim3(16, 8), 256, 0, stream>>>(
      wp2T, wp1b, WcT, nullptr, 1024, 1024, 1024);

  // fused QKV projection; V columns written directly transposed to Vtb
  k_gemm_bt<128, bf16, true><<<dim3(24, 32), 256, 0, stream>>>(
      xb, W3T, QKVb, Vtb, MTOK, NE3, NE);

  // balanced causal flash attention (R6 structure)
  k_attn<<<dim3(256), 512, 0, stream>>>(QKVb, Vtb, attb);

  // single fused output projection: out = att * Wc
  k_gemm_out<<<dim3(16, 32), 256, 0, stream>>>(attb, WcT, out);
}